// Round 10
// baseline (196.719 us; speedup 1.0000x reference)
//
#include <hip/hip_runtime.h>

typedef __attribute__((ext_vector_type(8))) short short8;
typedef __attribute__((ext_vector_type(4))) float float4v;
typedef __attribute__((ext_vector_type(4))) unsigned int uint4v;
typedef __attribute__((ext_vector_type(4))) unsigned short ushort4v;

__device__ __forceinline__ float lrelu(float v) { return v >= 0.f ? v : 0.01f * v; }

__device__ __forceinline__ unsigned short f2bf(float x) {
    union { float f; unsigned u; } c; c.f = x;
    unsigned r = (c.u + 0x7FFFu + ((c.u >> 16) & 1u)) >> 16;
    return (unsigned short)r;
}
__device__ __forceinline__ float bf2f(unsigned short h) {
    union { unsigned u; float f; } c; c.u = ((unsigned)h) << 16;
    return c.f;
}

// async global->LDS, 16B per lane. LDS dest must be wave-uniform base
// (HW adds lane*16); global src is per-lane (pre-swizzled).
__device__ __forceinline__ void gload16(const unsigned short* g, unsigned short* l) {
    __builtin_amdgcn_global_load_lds(
        (const __attribute__((address_space(1))) unsigned int*)g,
        (__attribute__((address_space(3))) unsigned int*)l, 16, 0, 0);
}

// ===========================================================================
// Shared MFMA core: C[128x128] += A[128xK] * B[128xK]^T, K=512, split-bf16
// (hi*hi + hi*lo + lo*hi -> ~fp32 precision). 256 threads, 4 waves 2x2.
// LDS: 4 tiles [128][64] bf16. global_load_lds direct staging: LDS linear,
// global source pre-swizzled with the same XOR involution the reads use.
// ===========================================================================
__device__ __forceinline__ void mfma_core(
    const unsigned short* __restrict__ Ah, const unsigned short* __restrict__ Al, int lda,
    const unsigned short* __restrict__ Bh, const unsigned short* __restrict__ Bl, int ldb,
    unsigned short* lds, float4v acc[4][4]) {
    const int tid = threadIdx.x;
    const int lane = tid & 63, wave = tid >> 6;
    const int wm = wave >> 1, wn = wave & 1;
    const int l15 = lane & 15, lhi = lane >> 4;
    unsigned short* LAh = lds;
    unsigned short* LAl = lds + 8192;
    unsigned short* LBh = lds + 16384;
    unsigned short* LBl = lds + 24576;

    for (int k0 = 0; k0 < 512; k0 += 64) {
#pragma unroll
        for (int tile = 0; tile < 4; ++tile) {
            const unsigned short* s = (tile == 0) ? Ah : (tile == 1) ? Al : (tile == 2) ? Bh : Bl;
            int ld = (tile < 2) ? lda : ldb;
            unsigned short* dbase = lds + tile * 8192;
#pragma unroll
            for (int it = 0; it < 4; ++it) {
                int idx = it * 256 + tid;
                int row = idx >> 3, ch = idx & 7;
                // linear LDS dest (wave-uniform base), swizzled global src
                gload16(&s[row * ld + k0 + ((ch ^ (row & 7)) << 3)],
                        dbase + ((it * 256 + wave * 64) << 3));
            }
        }
        __syncthreads();
#pragma unroll
        for (int ks = 0; ks < 2; ++ks) {
            short8 ah[4], al[4], bh[4], bl[4];
#pragma unroll
            for (int m = 0; m < 4; ++m) {
                int r = wm * 64 + m * 16 + l15;
                int off = r * 64 + (((ks * 4 + lhi) ^ (r & 7)) * 8);
                ah[m] = *(const short8*)&LAh[off];
                al[m] = *(const short8*)&LAl[off];
            }
#pragma unroll
            for (int n = 0; n < 4; ++n) {
                int r = wn * 64 + n * 16 + l15;
                int off = r * 64 + (((ks * 4 + lhi) ^ (r & 7)) * 8);
                bh[n] = *(const short8*)&LBh[off];
                bl[n] = *(const short8*)&LBl[off];
            }
#pragma unroll
            for (int m = 0; m < 4; ++m)
#pragma unroll
                for (int n = 0; n < 4; ++n) {
                    acc[m][n] = __builtin_amdgcn_mfma_f32_16x16x32_bf16(ah[m], bh[n], acc[m][n], 0, 0, 0);
                    acc[m][n] = __builtin_amdgcn_mfma_f32_16x16x32_bf16(ah[m], bl[n], acc[m][n], 0, 0, 0);
                    acc[m][n] = __builtin_amdgcn_mfma_f32_16x16x32_bf16(al[m], bh[n], acc[m][n], 0, 0, 0);
                }
        }
        __syncthreads();
    }
}

// ---------------------------------------------------------------------------
// Straight split to bf16 hi/lo: z=0 W_w, z=1 p1_w, z=2 p2_w. grid (256,3).
// ---------------------------------------------------------------------------
__global__ __launch_bounds__(256) void k_split_w(
    const float* __restrict__ ww, const float* __restrict__ p1w,
    const float* __restrict__ p2w, unsigned short* __restrict__ WwH,
    unsigned short* __restrict__ WwL, unsigned short* __restrict__ p1h,
    unsigned short* __restrict__ p1l, unsigned short* __restrict__ p2h,
    unsigned short* __restrict__ p2l) {
    int z = blockIdx.y;
    const float* src = (z == 0) ? ww : (z == 1) ? p1w : p2w;
    unsigned short* dh = (z == 0) ? WwH : (z == 1) ? p1h : p2h;
    unsigned short* dl = (z == 0) ? WwL : (z == 1) ? p1l : p2l;
    int i4 = blockIdx.x * 256 + threadIdx.x;
    float4v v = ((const float4v*)src)[i4];
    ushort4v h, l;
#pragma unroll
    for (int j = 0; j < 4; ++j) {
        h[j] = f2bf(v[j]);
        l[j] = f2bf(v[j] - bf2f(h[j]));
    }
    ((ushort4v*)dh)[i4] = h;
    ((ushort4v*)dl)[i4] = l;
}

// ---------------------------------------------------------------------------
// Transpose+split 512x512 weights: Dst[i][k] = src[k][i] as bf16 hi/lo.
// z=0 theta->Tt, z=1 phi->Pt, z=2 g_w->Gt. grid (16,16,3), block (32,8).
// ---------------------------------------------------------------------------
__global__ __launch_bounds__(256) void k_split_wT(
    const float* __restrict__ tw, const float* __restrict__ fw,
    const float* __restrict__ gw, unsigned short* __restrict__ TtH,
    unsigned short* __restrict__ TtL, unsigned short* __restrict__ PtH,
    unsigned short* __restrict__ PtL, unsigned short* __restrict__ GtH,
    unsigned short* __restrict__ GtL) {
    int z = blockIdx.z;
    const float* src = (z == 0) ? tw : (z == 1) ? fw : gw;
    unsigned short* dh = (z == 0) ? TtH : (z == 1) ? PtH : GtH;
    unsigned short* dl = (z == 0) ? TtL : (z == 1) ? PtL : GtL;
    int i0 = blockIdx.x * 32, k0 = blockIdx.y * 32;
    __shared__ float tile[32][33];
    int tx = threadIdx.x, ty = threadIdx.y;
#pragma unroll
    for (int i = 0; i < 4; ++i)
        tile[ty + i * 8][tx] = src[(k0 + ty + i * 8) * 512 + i0 + tx];
    __syncthreads();
#pragma unroll
    for (int i = 0; i < 4; ++i) {
        int row = i0 + ty + i * 8;
        float v = tile[tx][ty + i * 8];  // = src[k0+tx][row]
        unsigned short h = f2bf(v), l = f2bf(v - bf2f(h));
        int idx = row * 512 + k0 + tx;
        dh[idx] = h;
        dl[idx] = l;
    }
}

// ---------------------------------------------------------------------------
// Weight GEMMs via MFMA, epilogue splits into stacked Whi/Wlo [1024][512]:
//   z=1: Mw   = Tt . Pt^T -> rows 0-511    (Mw[i][j] = sum_k theta[k][i] phi[k][j])
//   z=0: Wg_w = Ww . Gt^T -> rows 512-1023 (Wg_w[i][j] = sum_k W_w[i][k] g_w[k][j])
// grid (4,4,2), block 256.
// ---------------------------------------------------------------------------
__global__ __launch_bounds__(256) void k_wgemm(
    const unsigned short* __restrict__ WwH, const unsigned short* __restrict__ WwL,
    const unsigned short* __restrict__ GtH, const unsigned short* __restrict__ GtL,
    const unsigned short* __restrict__ TtH, const unsigned short* __restrict__ TtL,
    const unsigned short* __restrict__ PtH, const unsigned short* __restrict__ PtL,
    unsigned short* __restrict__ Whi, unsigned short* __restrict__ Wlo) {
    __shared__ unsigned short lds[32768];
    int i0 = blockIdx.y * 128, j0 = blockIdx.x * 128;
    bool wg = blockIdx.z == 0;
    const unsigned short* Ah = (wg ? WwH : TtH) + i0 * 512;
    const unsigned short* Al = (wg ? WwL : TtL) + i0 * 512;
    const unsigned short* Bh = (wg ? GtH : PtH) + j0 * 512;
    const unsigned short* Bl = (wg ? GtL : PtL) + j0 * 512;
    float4v acc[4][4];
#pragma unroll
    for (int m = 0; m < 4; ++m)
#pragma unroll
        for (int n = 0; n < 4; ++n) acc[m][n] = (float4v){0.f, 0.f, 0.f, 0.f};

    mfma_core(Ah, Al, 512, Bh, Bl, 512, lds, acc);

    int lane = threadIdx.x & 63, wave = threadIdx.x >> 6;
    int wm = wave >> 1, wn = wave & 1, l15 = lane & 15, lhi = lane >> 4;
    int rowbase = wg ? 512 + i0 : i0;
#pragma unroll
    for (int m = 0; m < 4; ++m)
#pragma unroll
        for (int n = 0; n < 4; ++n) {
            int bcol = j0 + wn * 64 + n * 16 + l15;
#pragma unroll
            for (int i = 0; i < 4; ++i) {
                int r = rowbase + wm * 64 + m * 16 + lhi * 4 + i;
                float v = acc[m][n][i];
                unsigned short h = f2bf(v), l = f2bf(v - bf2f(h));
                Whi[r * 512 + bcol] = h;
                Wlo[r * 512 + bcol] = l;
            }
        }
}

// ---------------------------------------------------------------------------
// Transpose+split inputs: Xt[((b*128+t)*3+k)*512 + c] = in_k[b][c][t] (hi/lo)
// ---------------------------------------------------------------------------
__global__ __launch_bounds__(256) void k_splitx(const float* __restrict__ o1,
                                                const float* __restrict__ o2,
                                                const float* __restrict__ o3,
                                                unsigned short* __restrict__ Xh,
                                                unsigned short* __restrict__ Xl) {
    int z = blockIdx.z;
    int b = z / 3, k = z - b * 3;
    const float* In = (k == 0) ? o1 : ((k == 1) ? o2 : o3);
    int c0 = blockIdx.x * 32, t0 = blockIdx.y * 32;
    __shared__ float tile[32][33];
    int tx = threadIdx.x, ty = threadIdx.y;
#pragma unroll
    for (int i = 0; i < 4; ++i)
        tile[ty + i * 8][tx] = In[(b * 512 + c0 + ty + i * 8) * 128 + t0 + tx];
    __syncthreads();
#pragma unroll
    for (int i = 0; i < 4; ++i) {
        int t = t0 + ty + i * 8;
        float v = tile[tx][ty + i * 8];
        unsigned short h = f2bf(v), l = f2bf(v - bf2f(h));
        int idx = ((b * 128 + t) * 3 + k) * 512 + c0 + tx;
        Xh[idx] = h;
        Xl[idx] = l;
    }
}

// ---------------------------------------------------------------------------
// Stage A via MFMA: grid (48, 8): x = b*3+kin, y = o-tile
//   y 0-3 -> Y = Mw . x (bf16 hi/lo), y 4-7 -> Wg = Wg_w . x (fp32)
// ---------------------------------------------------------------------------
__global__ __launch_bounds__(256) void k_ga(
    const unsigned short* __restrict__ Whi, const unsigned short* __restrict__ Wlo,
    const unsigned short* __restrict__ Xh, const unsigned short* __restrict__ Xl,
    unsigned short* __restrict__ Yh, unsigned short* __restrict__ Yl,
    float* __restrict__ Wg) {
    __shared__ unsigned short lds[32768];
    int bk = blockIdx.x, y = blockIdx.y;
    int b = bk / 3, kin = bk - b * 3;
    int bbase = (b * 384 + kin) * 512;
    float4v acc[4][4];
#pragma unroll
    for (int m = 0; m < 4; ++m)
#pragma unroll
        for (int n = 0; n < 4; ++n) acc[m][n] = (float4v){0.f, 0.f, 0.f, 0.f};

    mfma_core(Whi + y * 128 * 512, Wlo + y * 128 * 512, 512,
              Xh + bbase, Xl + bbase, 1536, lds, acc);

    int lane = threadIdx.x & 63, wave = threadIdx.x >> 6;
    int wm = wave >> 1, wn = wave & 1, l15 = lane & 15, lhi = lane >> 4;
    int wsel = y >> 2, o0 = (y & 3) * 128;
#pragma unroll
    for (int m = 0; m < 4; ++m)
#pragma unroll
        for (int n = 0; n < 4; ++n) {
            int o_in = wm * 64 + m * 16 + lhi * 4;
            int t = wn * 64 + n * 16 + l15;
            int idx = bbase + t * 1536 + o0 + o_in;
            if (wsel == 1) {
                *(float4v*)&Wg[idx] = acc[m][n];
            } else {
                ushort4v h, l;
#pragma unroll
                for (int i = 0; i < 4; ++i) {
                    float v = acc[m][n][i];
                    h[i] = f2bf(v);
                    l[i] = f2bf(v - bf2f(h[i]));
                }
                *(ushort4v*)&Yh[idx] = h;
                *(ushort4v*)&Yl[idx] = l;
            }
        }
}

// ---------------------------------------------------------------------------
// Gram via MFMA: D[mat][t1][t2] = X[b,t1,k,:] . Y[b,t2,kp,:]
// grid 144, XCD-swizzled so same-b mats share an XCD's L2.
// ---------------------------------------------------------------------------
__global__ __launch_bounds__(256) void k_gram2(
    const unsigned short* __restrict__ Xh, const unsigned short* __restrict__ Xl,
    const unsigned short* __restrict__ Yh, const unsigned short* __restrict__ Yl,
    float* __restrict__ D) {
    __shared__ unsigned short lds[32768];
    int orig = blockIdx.x;
    int mat = (orig & 7) * 18 + (orig >> 3);  // 144 = 8 * 18, bijective
    int b = mat / 9, r9 = mat - b * 9, k = r9 / 3, kp = r9 - k * 3;
    int Ab = (b * 384 + k) * 512, Bb = (b * 384 + kp) * 512;
    float4v acc[4][4];
#pragma unroll
    for (int m = 0; m < 4; ++m)
#pragma unroll
        for (int n = 0; n < 4; ++n) acc[m][n] = (float4v){0.f, 0.f, 0.f, 0.f};

    mfma_core(Xh + Ab, Xl + Ab, 1536, Yh + Bb, Yl + Bb, 1536, lds, acc);

    int lane = threadIdx.x & 63, wave = threadIdx.x >> 6;
    int wm = wave >> 1, wn = wave & 1, l15 = lane & 15, lhi = lane >> 4;
    float* Dm = D + mat * 16384;
#pragma unroll
    for (int m = 0; m < 4; ++m)
#pragma unroll
        for (int n = 0; n < 4; ++n) {
            int t2 = wn * 64 + n * 16 + l15;
#pragma unroll
            for (int i = 0; i < 4; ++i) {
                int t1 = wm * 64 + m * 16 + lhi * 4 + i;
                Dm[t1 * 128 + t2] = acc[m][n][i];
            }
        }
}

// ---------------------------------------------------------------------------
// MLP layer via MFMA: C[r][o] = lrelu( A[r,:] . W[o,:] )
// ---------------------------------------------------------------------------
template <bool SPLIT_OUT>
__global__ __launch_bounds__(256) void k_mlp(
    const unsigned short* __restrict__ Ahi, const unsigned short* __restrict__ Alo,
    const unsigned short* __restrict__ Bhi, const unsigned short* __restrict__ Blo,
    unsigned short* __restrict__ Ch, unsigned short* __restrict__ Cl,
    float* __restrict__ Cf) {
    __shared__ unsigned short lds[32768];
    int r0 = blockIdx.x * 128, o0 = blockIdx.y * 128;
    float4v acc[4][4];
#pragma unroll
    for (int m = 0; m < 4; ++m)
#pragma unroll
        for (int n = 0; n < 4; ++n) acc[m][n] = (float4v){0.f, 0.f, 0.f, 0.f};

    mfma_core(Ahi + r0 * 512, Alo + r0 * 512, 512, Bhi + o0 * 512, Blo + o0 * 512, 512, lds, acc);

    int lane = threadIdx.x & 63, wave = threadIdx.x >> 6;
    int wm = wave >> 1, wn = wave & 1, l15 = lane & 15, lhi = lane >> 4;
#pragma unroll
    for (int m = 0; m < 4; ++m)
#pragma unroll
        for (int n = 0; n < 4; ++n) {
            int o = o0 + wn * 64 + n * 16 + l15;
#pragma unroll
            for (int i = 0; i < 4; ++i) {
                int r = r0 + wm * 64 + m * 16 + lhi * 4 + i;
                float v = lrelu(acc[m][n][i]);
                if (SPLIT_OUT) {
                    unsigned short h = f2bf(v), l = f2bf(v - bf2f(h));
                    Ch[r * 512 + o] = h;
                    Cl[r * 512 + o] = l;
                } else {
                    Cf[r * 512 + o] = v;
                }
            }
        }
}

// ---------------------------------------------------------------------------
// Mix via MFMA: per (b,t): gather f 24x24 from D, softmax -> P (hi/lo bf16,
// padded 32x32), wg window (24x512) -> LDS [o][m] bf16-hi. Then per o-tile:
// y[n][o] = P . wg via mfma, epilogue adds W_b + X residual, maxes over n.
// grid 2048 XCD-swizzled, block 256 (4 waves, 8 o-tiles each).
// FIX r9->r10: zero Lw pad columns m=24..31 (read by MFMA k-chunks, were
// uninitialized LDS -> garbage through the pool-max).
// ---------------------------------------------------------------------------
__global__ __launch_bounds__(256) void k_mix2(
    const unsigned short* __restrict__ Xh, const unsigned short* __restrict__ Xl,
    const float* __restrict__ Wg, const float* __restrict__ D,
    const float* __restrict__ W_b, unsigned short* __restrict__ Plh,
    unsigned short* __restrict__ Pll) {
    int orig = blockIdx.x;
    int bid = ((orig & 7) << 8) | (orig >> 3);  // 2048 = 8 * 256, bijective
    int b = bid >> 7, t = bid & 127;
    int tid = threadIdx.x;

    __shared__ float Pm[24][28];
    __shared__ unsigned short Pwh[32][40];  // P hi, rows n (pad), cols m (pad)
    __shared__ unsigned short Pwl[32][40];  // P lo
    __shared__ unsigned short Lw[512][40];  // wg bf16-hi, [o][m]

    // zero P pads (full array) and Lw pad columns m=24..31
    for (int i = tid; i < 32 * 40 / 2; i += 256) {
        ((unsigned*)Pwh)[i] = 0u;
        ((unsigned*)Pwl)[i] = 0u;
    }
    for (int r = tid; r < 512; r += 256) {
        *(uint4v*)&Lw[r][24] = (uint4v){0u, 0u, 0u, 0u};  // m = 24..31
    }
    // stage wg window -> LDS [o][m] (bf16 hi only)
#pragma unroll
    for (int r = 0; r < 48; ++r) {
        int flat = r * 256 + tid;
        int m = flat >> 9, o = flat & 511;
        int jp = m / 3, kp = m - jp * 3;
        int tp = t - 7 + jp;
        float v = (tp >= 0) ? Wg[(((b * 128 + tp) * 3 + kp) << 9) + o] : 0.f;
        Lw[o][m] = f2bf(v);
    }
    // gather f from D
    for (int idx = tid; idx < 576; idx += 256) {
        int n = idx / 24, m = idx - n * 24;
        int j = n / 3, k = n - j * 3;
        int jp = m / 3, kp = m - jp * 3;
        int t1 = t - 7 + j, t2 = t - 7 + jp;
        float v = 0.f;
        if (t1 >= 0 && t2 >= 0)
            v = D[((((b * 3 + k) * 3 + kp) * 128 + t1) << 7) + t2];
        Pm[n][m] = v;
    }
    __syncthreads();

    // softmax rows -> P bf16 hi/lo
    if (tid < 24) {
        float mx = -1e30f;
#pragma unroll
        for (int m = 0; m < 24; ++m) mx = fmaxf(mx, Pm[tid][m]);
        float e[24], sum = 0.f;
#pragma unroll
        for (int m = 0; m < 24; ++m) { e[m] = __expf(Pm[tid][m] - mx); sum += e[m]; }
        float inv = 1.0f / sum;
#pragma unroll
        for (int m = 0; m < 24; ++m) {
            float p = e[m] * inv;
            unsigned short h = f2bf(p);
            Pwh[tid][m] = h;
            Pwl[tid][m] = f2bf(p - bf2f(h));
        }
    }
    __syncthreads();

    int lane = tid & 63, wave = tid >> 6;
    int l15 = lane & 15, lhi = lane >> 4;
    // A-frags (P): row = l15, k-chunk = lhi*8
    short8 a0h = *(const short8*)&Pwh[l15][lhi * 8];
    short8 a0l = *(const short8*)&Pwl[l15][lhi * 8];
    short8 a1h = *(const short8*)&Pwh[16 + l15][lhi * 8];
    short8 a1l = *(const short8*)&Pwl[16 + l15][lhi * 8];

    for (int q = 0; q < 8; ++q) {
        int ot = q * 4 + wave;       // o-tile 0..31
        int o = ot * 16 + l15;
        short8 bw = *(const short8*)&Lw[o][lhi * 8];
        float4v acc0 = {0.f, 0.f, 0.f, 0.f};
        float4v acc1 = {0.f, 0.f, 0.f, 0.f};
        acc0 = __builtin_amdgcn_mfma_f32_16x16x32_bf16(a0h, bw, acc0, 0, 0, 0);
        acc0 = __builtin_amdgcn_mfma_f32_16x16x32_bf16(a0l, bw, acc0, 0, 0, 0);
        acc1 = __builtin_amdgcn_mfma_f32_16x16x32_bf16(a1h, bw, acc1, 0, 0, 0);
        acc1 = __builtin_amdgcn_mfma_f32_16x16x32_bf16(a1l, bw, acc1, 0, 0, 0);

        float wb = W_b[o];
        float pool = -1e30f;
#pragma unroll
        for (int i = 0; i < 4; ++i) {
            {   // n-tile 0: n = lhi*4 + i (0..15, always valid)
                int n = lhi * 4 + i;
                int j = n / 3, kk = n - j * 3;
                int tp = t - 7 + j;
                float xw = 0.f;
                if (tp >= 0) {
                    int base = (((b * 128 + tp) * 3 + kk) << 9) + o;
                    xw = bf2f(Xh[base]) + bf2f(Xl[base]);
                }
                pool = fmaxf(pool, acc0[i] + wb + xw);
            }
            {   // n-tile 1: n = 16 + lhi*4 + i (valid only < 24)
                int n = 16 + lhi * 4 + i;
                if (n < 24) {
                    int j = n / 3, kk = n - j * 3;
                    int tp = t - 7 + j;
                    float xw = 0.f;
                    if (tp >= 0) {
                        int base = (((b * 128 + tp) * 3 + kk) << 9) + o;
                        xw = bf2f(Xh[base]) + bf2f(Xl[base]);
                    }
                    pool = fmaxf(pool, acc1[i] + wb + xw);
                }
            }
        }
        // combine across lhi groups (lanes l15+16k share the same o)
        pool = fmaxf(pool, __shfl_xor(pool, 16, 64));
        pool = fmaxf(pool, __shfl_xor(pool, 32, 64));
        if (lhi == 0) {
            int oidx = ((t * 16 + b) << 9) + o;
            unsigned short h = f2bf(pool), l = f2bf(pool - bf2f(h));
            Plh[oidx] = h;
            Pll[oidx] = l;
        }
    }
}

// ---------------------------------------------------------------------------
// out[r] = lrelu( sum_c H[r][c]*p3w[c] + p3b )   one wave per row
// ---------------------------------------------------------------------------
__global__ __launch_bounds__(256) void k_final(const float* __restrict__ H,
                                               const float* __restrict__ p3w,
                                               const float* __restrict__ p3b,
                                               float* __restrict__ out) {
    int r = blockIdx.x * 4 + (threadIdx.x >> 6);
    int lane = threadIdx.x & 63;
    const float4* h4 = (const float4*)&H[r << 9];
    const float4* w4 = (const float4*)p3w;
    float4 a1 = h4[lane], a2 = h4[lane + 64];
    float4 b1 = w4[lane], b2 = w4[lane + 64];
    float s = a1.x * b1.x + a1.y * b1.y + a1.z * b1.z + a1.w * b1.w +
              a2.x * b2.x + a2.y * b2.y + a2.z * b2.z + a2.w * b2.w;
#pragma unroll
    for (int off = 32; off; off >>= 1) s += __shfl_down(s, off, 64);
    if (lane == 0) out[r] = lrelu(s + p3b[0]);
}

extern "C" void kernel_launch(void* const* d_in, const int* in_sizes, int n_in,
                              void* d_out, int out_size, void* d_ws, size_t ws_size,
                              hipStream_t stream) {
    const float* out1 = (const float*)d_in[0];
    const float* out2 = (const float*)d_in[1];
    const float* out3 = (const float*)d_in[2];
    const float* theta_w = (const float*)d_in[3];
    const float* phi_w = (const float*)d_in[4];
    const float* g_w = (const float*)d_in[5];
    const float* W_w = (const float*)d_in[6];
    const float* W_b = (const float*)d_in[7];
    const float* p1_w = (const float*)d_in[8];
    const float* p2_w = (const float*)d_in[9];
    const float* p3_w = (const float*)d_in[10];
    const float* p3_b = (const float*)d_in[11];
    float* outp = (float*)d_out;

    // ---- workspace layout (bytes) ----
    char* wsb = (char*)d_ws;
    unsigned short* Whi = (unsigned short*)(wsb + 0);         // 1024x512 bf16 (Mw | Wg_w)
    unsigned short* Wlo = (unsigned short*)(wsb + 1048576);
    unsigned short* p1h = (unsigned short*)(wsb + 2097152);
    unsigned short* p1l = (unsigned short*)(wsb + 2621440);
    unsigned short* p2h = (unsigned short*)(wsb + 3145728);
    unsigned short* p2l = (unsigned short*)(wsb + 3670016);
    unsigned short* WwH = (unsigned short*)(wsb + 4194304);
    unsigned short* WwL = (unsigned short*)(wsb + 4718592);
    unsigned short* TtH = (unsigned short*)(wsb + 5242880);
    unsigned short* TtL = (unsigned short*)(wsb + 5767168);
    unsigned short* PtH = (unsigned short*)(wsb + 6291456);
    unsigned short* PtL = (unsigned short*)(wsb + 6815744);
    unsigned short* GtH = (unsigned short*)(wsb + 7340032);
    unsigned short* GtL = (unsigned short*)(wsb + 7864320);
    unsigned short* Xh  = (unsigned short*)(wsb + 8388608);   // 6144x512 bf16
    unsigned short* Xl  = (unsigned short*)(wsb + 14680064);
    unsigned short* Yh  = (unsigned short*)(wsb + 20971520);  // 6144x512 bf16
    unsigned short* Yl  = (unsigned short*)(wsb + 27262976);
    float* Wg = (float*)(wsb + 33554432);                     // 6144x512 fp32
    float* D  = (float*)(wsb + 46137344);                     // 144x128x128 fp32
    // aliases (dead-buffer reuse):
    unsigned short* Plh = (unsigned short*)(wsb + 20971520);  // over Yh (dead after gram)
    unsigned short* Pll = (unsigned short*)(wsb + 23068672);
    unsigned short* h1h = (unsigned short*)(wsb + 27262976);  // over Yl (dead after gram)
    unsigned short* h1l = (unsigned short*)(wsb + 29360128);
    float* h2 = (float*)(wsb + 8388608);                      // over Xh (dead after mix)

    // 1. split raw weights: straight (W_w, p1, p2) + transposed (theta, phi, g)
    k_split_w<<<dim3(256, 3), 256, 0, stream>>>(W_w, p1_w, p2_w,
                                                WwH, WwL, p1h, p1l, p2h, p2l);
    k_split_wT<<<dim3(16, 16, 3), dim3(32, 8), 0, stream>>>(theta_w, phi_w, g_w,
                                                            TtH, TtL, PtH, PtL, GtH, GtL);
    // 2. transpose+split inputs (independent of weight GEMMs)
    k_splitx<<<dim3(16, 4, 48), dim3(32, 8), 0, stream>>>(out1, out2, out3, Xh, Xl);
    // 3. weight GEMMs via MFMA: Mw = Tt.Pt^T ; Wg_w = Ww.Gt^T -> Whi/Wlo stacked
    k_wgemm<<<dim3(4, 4, 2), 256, 0, stream>>>(WwH, WwL, GtH, GtL, TtH, TtL,
                                               PtH, PtL, Whi, Wlo);
    // 4. stage A: Y (bf16 hi/lo) + Wg (fp32)
    k_ga<<<dim3(48, 8), 256, 0, stream>>>(Whi, Wlo, Xh, Xl, Yh, Yl, Wg);
    // 5. gram matrices: D = X . Y^T
    k_gram2<<<dim3(144), 256, 0, stream>>>(Xh, Xl, Yh, Yl, D);
    // 6. softmax + mix + residual + pool (MFMA)
    k_mix2<<<dim3(2048), 256, 0, stream>>>(Xh, Xl, Wg, D, W_b, Plh, Pll);
    // 7. MLP
    k_mlp<true><<<dim3(16, 4), 256, 0, stream>>>(Plh, Pll, p1h, p1l, h1h, h1l, nullptr);
    k_mlp<false><<<dim3(16, 4), 256, 0, stream>>>(h1h, h1l, p2h, p2l, nullptr, nullptr, h2);
    // 8. final projection
    k_final<<<dim3(512), 256, 0, stream>>>(h2, p3_w, p3_b, outp);
}

// Round 11
// 155.111 us; speedup vs baseline: 1.2682x; 1.2682x over previous
//
#include <hip/hip_runtime.h>

typedef __attribute__((ext_vector_type(8))) short short8;
typedef __attribute__((ext_vector_type(4))) float float4v;
typedef __attribute__((ext_vector_type(4))) unsigned int uint4v;
typedef __attribute__((ext_vector_type(4))) unsigned short ushort4v;

__device__ __forceinline__ float lrelu(float v) { return v >= 0.f ? v : 0.01f * v; }

__device__ __forceinline__ unsigned short f2bf(float x) {
    union { float f; unsigned u; } c; c.f = x;
    unsigned r = (c.u + 0x7FFFu + ((c.u >> 16) & 1u)) >> 16;
    return (unsigned short)r;
}
__device__ __forceinline__ float bf2f(unsigned short h) {
    union { unsigned u; float f; } c; c.u = ((unsigned)h) << 16;
    return c.f;
}

// async global->LDS, 16B per lane. LDS dest must be wave-uniform base
// (HW adds lane*16); global src is per-lane (pre-swizzled).
__device__ __forceinline__ void gload16(const unsigned short* g, unsigned short* l) {
    __builtin_amdgcn_global_load_lds(
        (const __attribute__((address_space(1))) unsigned int*)g,
        (__attribute__((address_space(3))) unsigned int*)l, 16, 0, 0);
}

// ===========================================================================
// Shared MFMA core: C[128x128] += A[128xK] * B[128xK]^T, K=512, split-bf16
// (hi*hi + hi*lo + lo*hi -> ~fp32 precision). 256 threads, 4 waves 2x2.
// LDS: 4 tiles [128][64] bf16. global_load_lds direct staging: LDS linear,
// global source pre-swizzled with the same XOR involution the reads use.
// ===========================================================================
__device__ __forceinline__ void mfma_core(
    const unsigned short* __restrict__ Ah, const unsigned short* __restrict__ Al, int lda,
    const unsigned short* __restrict__ Bh, const unsigned short* __restrict__ Bl, int ldb,
    unsigned short* lds, float4v acc[4][4]) {
    const int tid = threadIdx.x;
    const int lane = tid & 63, wave = tid >> 6;
    const int wm = wave >> 1, wn = wave & 1;
    const int l15 = lane & 15, lhi = lane >> 4;
    unsigned short* LAh = lds;
    unsigned short* LAl = lds + 8192;
    unsigned short* LBh = lds + 16384;
    unsigned short* LBl = lds + 24576;

    for (int k0 = 0; k0 < 512; k0 += 64) {
#pragma unroll
        for (int tile = 0; tile < 4; ++tile) {
            const unsigned short* s = (tile == 0) ? Ah : (tile == 1) ? Al : (tile == 2) ? Bh : Bl;
            int ld = (tile < 2) ? lda : ldb;
            unsigned short* dbase = lds + tile * 8192;
#pragma unroll
            for (int it = 0; it < 4; ++it) {
                int idx = it * 256 + tid;
                int row = idx >> 3, ch = idx & 7;
                // linear LDS dest (wave-uniform base), swizzled global src
                gload16(&s[row * ld + k0 + ((ch ^ (row & 7)) << 3)],
                        dbase + ((it * 256 + wave * 64) << 3));
            }
        }
        __syncthreads();
#pragma unroll
        for (int ks = 0; ks < 2; ++ks) {
            short8 ah[4], al[4], bh[4], bl[4];
#pragma unroll
            for (int m = 0; m < 4; ++m) {
                int r = wm * 64 + m * 16 + l15;
                int off = r * 64 + (((ks * 4 + lhi) ^ (r & 7)) * 8);
                ah[m] = *(const short8*)&LAh[off];
                al[m] = *(const short8*)&LAl[off];
            }
#pragma unroll
            for (int n = 0; n < 4; ++n) {
                int r = wn * 64 + n * 16 + l15;
                int off = r * 64 + (((ks * 4 + lhi) ^ (r & 7)) * 8);
                bh[n] = *(const short8*)&LBh[off];
                bl[n] = *(const short8*)&LBl[off];
            }
#pragma unroll
            for (int m = 0; m < 4; ++m)
#pragma unroll
                for (int n = 0; n < 4; ++n) {
                    acc[m][n] = __builtin_amdgcn_mfma_f32_16x16x32_bf16(ah[m], bh[n], acc[m][n], 0, 0, 0);
                    acc[m][n] = __builtin_amdgcn_mfma_f32_16x16x32_bf16(ah[m], bl[n], acc[m][n], 0, 0, 0);
                    acc[m][n] = __builtin_amdgcn_mfma_f32_16x16x32_bf16(al[m], bh[n], acc[m][n], 0, 0, 0);
                }
        }
        __syncthreads();
    }
}

// ---------------------------------------------------------------------------
// Straight split to bf16 hi/lo: z=0 W_w, z=1 p1_w, z=2 p2_w. grid (256,3).
// ---------------------------------------------------------------------------
__global__ __launch_bounds__(256) void k_split_w(
    const float* __restrict__ ww, const float* __restrict__ p1w,
    const float* __restrict__ p2w, unsigned short* __restrict__ WwH,
    unsigned short* __restrict__ WwL, unsigned short* __restrict__ p1h,
    unsigned short* __restrict__ p1l, unsigned short* __restrict__ p2h,
    unsigned short* __restrict__ p2l) {
    int z = blockIdx.y;
    const float* src = (z == 0) ? ww : (z == 1) ? p1w : p2w;
    unsigned short* dh = (z == 0) ? WwH : (z == 1) ? p1h : p2h;
    unsigned short* dl = (z == 0) ? WwL : (z == 1) ? p1l : p2l;
    int i4 = blockIdx.x * 256 + threadIdx.x;
    float4v v = ((const float4v*)src)[i4];
    ushort4v h, l;
#pragma unroll
    for (int j = 0; j < 4; ++j) {
        h[j] = f2bf(v[j]);
        l[j] = f2bf(v[j] - bf2f(h[j]));
    }
    ((ushort4v*)dh)[i4] = h;
    ((ushort4v*)dl)[i4] = l;
}

// ---------------------------------------------------------------------------
// Transpose+split 512x512 weights: Dst[i][k] = src[k][i] as bf16 hi/lo.
// z=0 theta->Tt, z=1 phi->Pt, z=2 g_w->Gt. grid (16,16,3), block (32,8).
// ---------------------------------------------------------------------------
__global__ __launch_bounds__(256) void k_split_wT(
    const float* __restrict__ tw, const float* __restrict__ fw,
    const float* __restrict__ gw, unsigned short* __restrict__ TtH,
    unsigned short* __restrict__ TtL, unsigned short* __restrict__ PtH,
    unsigned short* __restrict__ PtL, unsigned short* __restrict__ GtH,
    unsigned short* __restrict__ GtL) {
    int z = blockIdx.z;
    const float* src = (z == 0) ? tw : (z == 1) ? fw : gw;
    unsigned short* dh = (z == 0) ? TtH : (z == 1) ? PtH : GtH;
    unsigned short* dl = (z == 0) ? TtL : (z == 1) ? PtL : GtL;
    int i0 = blockIdx.x * 32, k0 = blockIdx.y * 32;
    __shared__ float tile[32][33];
    int tx = threadIdx.x, ty = threadIdx.y;
#pragma unroll
    for (int i = 0; i < 4; ++i)
        tile[ty + i * 8][tx] = src[(k0 + ty + i * 8) * 512 + i0 + tx];
    __syncthreads();
#pragma unroll
    for (int i = 0; i < 4; ++i) {
        int row = i0 + ty + i * 8;
        float v = tile[tx][ty + i * 8];  // = src[k0+tx][row]
        unsigned short h = f2bf(v), l = f2bf(v - bf2f(h));
        int idx = row * 512 + k0 + tx;
        dh[idx] = h;
        dl[idx] = l;
    }
}

// ---------------------------------------------------------------------------
// Weight GEMMs via MFMA, epilogue splits into stacked Whi/Wlo [1024][512]:
//   z=1: Mw   = Tt . Pt^T -> rows 0-511    (Mw[i][j] = sum_k theta[k][i] phi[k][j])
//   z=0: Wg_w = Ww . Gt^T -> rows 512-1023 (Wg_w[i][j] = sum_k W_w[i][k] g_w[k][j])
// grid (4,4,2), block 256.
// ---------------------------------------------------------------------------
__global__ __launch_bounds__(256) void k_wgemm(
    const unsigned short* __restrict__ WwH, const unsigned short* __restrict__ WwL,
    const unsigned short* __restrict__ GtH, const unsigned short* __restrict__ GtL,
    const unsigned short* __restrict__ TtH, const unsigned short* __restrict__ TtL,
    const unsigned short* __restrict__ PtH, const unsigned short* __restrict__ PtL,
    unsigned short* __restrict__ Whi, unsigned short* __restrict__ Wlo) {
    __shared__ unsigned short lds[32768];
    int i0 = blockIdx.y * 128, j0 = blockIdx.x * 128;
    bool wg = blockIdx.z == 0;
    const unsigned short* Ah = (wg ? WwH : TtH) + i0 * 512;
    const unsigned short* Al = (wg ? WwL : TtL) + i0 * 512;
    const unsigned short* Bh = (wg ? GtH : PtH) + j0 * 512;
    const unsigned short* Bl = (wg ? GtL : PtL) + j0 * 512;
    float4v acc[4][4];
#pragma unroll
    for (int m = 0; m < 4; ++m)
#pragma unroll
        for (int n = 0; n < 4; ++n) acc[m][n] = (float4v){0.f, 0.f, 0.f, 0.f};

    mfma_core(Ah, Al, 512, Bh, Bl, 512, lds, acc);

    int lane = threadIdx.x & 63, wave = threadIdx.x >> 6;
    int wm = wave >> 1, wn = wave & 1, l15 = lane & 15, lhi = lane >> 4;
    int rowbase = wg ? 512 + i0 : i0;
#pragma unroll
    for (int m = 0; m < 4; ++m)
#pragma unroll
        for (int n = 0; n < 4; ++n) {
            int bcol = j0 + wn * 64 + n * 16 + l15;
#pragma unroll
            for (int i = 0; i < 4; ++i) {
                int r = rowbase + wm * 64 + m * 16 + lhi * 4 + i;
                float v = acc[m][n][i];
                unsigned short h = f2bf(v), l = f2bf(v - bf2f(h));
                Whi[r * 512 + bcol] = h;
                Wlo[r * 512 + bcol] = l;
            }
        }
}

// ---------------------------------------------------------------------------
// Transpose+split inputs: Xt[((b*128+t)*3+k)*512 + c] = in_k[b][c][t] (hi/lo)
// ---------------------------------------------------------------------------
__global__ __launch_bounds__(256) void k_splitx(const float* __restrict__ o1,
                                                const float* __restrict__ o2,
                                                const float* __restrict__ o3,
                                                unsigned short* __restrict__ Xh,
                                                unsigned short* __restrict__ Xl) {
    int z = blockIdx.z;
    int b = z / 3, k = z - b * 3;
    const float* In = (k == 0) ? o1 : ((k == 1) ? o2 : o3);
    int c0 = blockIdx.x * 32, t0 = blockIdx.y * 32;
    __shared__ float tile[32][33];
    int tx = threadIdx.x, ty = threadIdx.y;
#pragma unroll
    for (int i = 0; i < 4; ++i)
        tile[ty + i * 8][tx] = In[(b * 512 + c0 + ty + i * 8) * 128 + t0 + tx];
    __syncthreads();
#pragma unroll
    for (int i = 0; i < 4; ++i) {
        int t = t0 + ty + i * 8;
        float v = tile[tx][ty + i * 8];
        unsigned short h = f2bf(v), l = f2bf(v - bf2f(h));
        int idx = ((b * 128 + t) * 3 + k) * 512 + c0 + tx;
        Xh[idx] = h;
        Xl[idx] = l;
    }
}

// ---------------------------------------------------------------------------
// Stage A via MFMA: grid (48, 8): x = b*3+kin, y = o-tile
//   y 0-3 -> Y = Mw . x (bf16 hi/lo), y 4-7 -> Wg = Wg_w . x (fp32)
// ---------------------------------------------------------------------------
__global__ __launch_bounds__(256) void k_ga(
    const unsigned short* __restrict__ Whi, const unsigned short* __restrict__ Wlo,
    const unsigned short* __restrict__ Xh, const unsigned short* __restrict__ Xl,
    unsigned short* __restrict__ Yh, unsigned short* __restrict__ Yl,
    float* __restrict__ Wg) {
    __shared__ unsigned short lds[32768];
    int bk = blockIdx.x, y = blockIdx.y;
    int b = bk / 3, kin = bk - b * 3;
    int bbase = (b * 384 + kin) * 512;
    float4v acc[4][4];
#pragma unroll
    for (int m = 0; m < 4; ++m)
#pragma unroll
        for (int n = 0; n < 4; ++n) acc[m][n] = (float4v){0.f, 0.f, 0.f, 0.f};

    mfma_core(Whi + y * 128 * 512, Wlo + y * 128 * 512, 512,
              Xh + bbase, Xl + bbase, 1536, lds, acc);

    int lane = threadIdx.x & 63, wave = threadIdx.x >> 6;
    int wm = wave >> 1, wn = wave & 1, l15 = lane & 15, lhi = lane >> 4;
    int wsel = y >> 2, o0 = (y & 3) * 128;
#pragma unroll
    for (int m = 0; m < 4; ++m)
#pragma unroll
        for (int n = 0; n < 4; ++n) {
            int o_in = wm * 64 + m * 16 + lhi * 4;
            int t = wn * 64 + n * 16 + l15;
            int idx = bbase + t * 1536 + o0 + o_in;
            if (wsel == 1) {
                *(float4v*)&Wg[idx] = acc[m][n];
            } else {
                ushort4v h, l;
#pragma unroll
                for (int i = 0; i < 4; ++i) {
                    float v = acc[m][n][i];
                    h[i] = f2bf(v);
                    l[i] = f2bf(v - bf2f(h[i]));
                }
                *(ushort4v*)&Yh[idx] = h;
                *(ushort4v*)&Yl[idx] = l;
            }
        }
}

// ---------------------------------------------------------------------------
// Gram via MFMA: D[mat][t1][t2] = X[b,t1,k,:] . Y[b,t2,kp,:]
// grid 144, XCD-swizzled so same-b mats share an XCD's L2.
// ---------------------------------------------------------------------------
__global__ __launch_bounds__(256) void k_gram2(
    const unsigned short* __restrict__ Xh, const unsigned short* __restrict__ Xl,
    const unsigned short* __restrict__ Yh, const unsigned short* __restrict__ Yl,
    float* __restrict__ D) {
    __shared__ unsigned short lds[32768];
    int orig = blockIdx.x;
    int mat = (orig & 7) * 18 + (orig >> 3);  // 144 = 8 * 18, bijective
    int b = mat / 9, r9 = mat - b * 9, k = r9 / 3, kp = r9 - k * 3;
    int Ab = (b * 384 + k) * 512, Bb = (b * 384 + kp) * 512;
    float4v acc[4][4];
#pragma unroll
    for (int m = 0; m < 4; ++m)
#pragma unroll
        for (int n = 0; n < 4; ++n) acc[m][n] = (float4v){0.f, 0.f, 0.f, 0.f};

    mfma_core(Xh + Ab, Xl + Ab, 1536, Yh + Bb, Yl + Bb, 1536, lds, acc);

    int lane = threadIdx.x & 63, wave = threadIdx.x >> 6;
    int wm = wave >> 1, wn = wave & 1, l15 = lane & 15, lhi = lane >> 4;
    float* Dm = D + mat * 16384;
#pragma unroll
    for (int m = 0; m < 4; ++m)
#pragma unroll
        for (int n = 0; n < 4; ++n) {
            int t2 = wn * 64 + n * 16 + l15;
#pragma unroll
            for (int i = 0; i < 4; ++i) {
                int t1 = wm * 64 + m * 16 + lhi * 4 + i;
                Dm[t1 * 128 + t2] = acc[m][n][i];
            }
        }
}

// ---------------------------------------------------------------------------
// MLP layer via MFMA: C[r][o] = lrelu( A[r,:] . W[o,:] )
// ---------------------------------------------------------------------------
template <bool SPLIT_OUT>
__global__ __launch_bounds__(256) void k_mlp(
    const unsigned short* __restrict__ Ahi, const unsigned short* __restrict__ Alo,
    const unsigned short* __restrict__ Bhi, const unsigned short* __restrict__ Blo,
    unsigned short* __restrict__ Ch, unsigned short* __restrict__ Cl,
    float* __restrict__ Cf) {
    __shared__ unsigned short lds[32768];
    int r0 = blockIdx.x * 128, o0 = blockIdx.y * 128;
    float4v acc[4][4];
#pragma unroll
    for (int m = 0; m < 4; ++m)
#pragma unroll
        for (int n = 0; n < 4; ++n) acc[m][n] = (float4v){0.f, 0.f, 0.f, 0.f};

    mfma_core(Ahi + r0 * 512, Alo + r0 * 512, 512, Bhi + o0 * 512, Blo + o0 * 512, 512, lds, acc);

    int lane = threadIdx.x & 63, wave = threadIdx.x >> 6;
    int wm = wave >> 1, wn = wave & 1, l15 = lane & 15, lhi = lane >> 4;
#pragma unroll
    for (int m = 0; m < 4; ++m)
#pragma unroll
        for (int n = 0; n < 4; ++n) {
            int o = o0 + wn * 64 + n * 16 + l15;
#pragma unroll
            for (int i = 0; i < 4; ++i) {
                int r = r0 + wm * 64 + m * 16 + lhi * 4 + i;
                float v = lrelu(acc[m][n][i]);
                if (SPLIT_OUT) {
                    unsigned short h = f2bf(v), l = f2bf(v - bf2f(h));
                    Ch[r * 512 + o] = h;
                    Cl[r * 512 + o] = l;
                } else {
                    Cf[r * 512 + o] = v;
                }
            }
        }
}

// ---------------------------------------------------------------------------
// Mix (round-8 proven body + XCD swizzle; r11: 4-way split accumulators to
// break the serial 24-FMA dependence chain per n). grid 2048, block 512.
// ---------------------------------------------------------------------------
__global__ __launch_bounds__(512) void k_mix(
    const unsigned short* __restrict__ Xh, const unsigned short* __restrict__ Xl,
    const float* __restrict__ Wg, const float* __restrict__ D,
    const float* __restrict__ W_b, unsigned short* __restrict__ Plh,
    unsigned short* __restrict__ Pll) {
    int orig = blockIdx.x;
    int bid = ((orig & 7) << 8) | (orig >> 3);  // 2048 = 8 * 256, bijective
    int b = bid >> 7, t = bid & 127;
    int tid = threadIdx.x;

    __shared__ float Pm[24][28];

    for (int idx = tid; idx < 576; idx += 512) {
        int n = idx / 24, m = idx - n * 24;
        int j = n / 3, k = n - j * 3;
        int jp = m / 3, kp = m - jp * 3;
        int t1 = t - 7 + j, t2 = t - 7 + jp;
        float v = 0.f;
        if (t1 >= 0 && t2 >= 0)
            v = D[((((b * 3 + k) * 3 + kp) * 128 + t1) << 7) + t2];
        Pm[n][m] = v;
    }
    __syncthreads();

    if (tid < 24) {
        float mx = -1e30f;
#pragma unroll
        for (int m = 0; m < 24; ++m) mx = fmaxf(mx, Pm[tid][m]);
        float e[24], sum = 0.f;
#pragma unroll
        for (int m = 0; m < 24; ++m) { e[m] = __expf(Pm[tid][m] - mx); sum += e[m]; }
        float inv = 1.0f / sum;
#pragma unroll
        for (int m = 0; m < 24; ++m) Pm[tid][m] = e[m] * inv;
    }
    __syncthreads();

    int o = tid;
    float wg[24], xw[24];
#pragma unroll
    for (int m = 0; m < 24; ++m) {
        int j = m / 3, k = m - j * 3;
        int tp = t - 7 + j;
        int base = (((b * 128 + tp) * 3 + k) << 9) + o;
        wg[m] = (tp >= 0) ? Wg[base] : 0.f;
        xw[m] = (tp >= 0) ? (bf2f(Xh[base]) + bf2f(Xl[base])) : 0.f;
    }
    float wb = W_b[o];
    float pooled = -1e30f;
#pragma unroll
    for (int n = 0; n < 24; ++n) {
        float s0 = 0.f, s1 = 0.f, s2 = 0.f, s3 = 0.f;
#pragma unroll
        for (int mq = 0; mq < 6; ++mq) {
            s0 += Pm[n][mq * 4 + 0] * wg[mq * 4 + 0];
            s1 += Pm[n][mq * 4 + 1] * wg[mq * 4 + 1];
            s2 += Pm[n][mq * 4 + 2] * wg[mq * 4 + 2];
            s3 += Pm[n][mq * 4 + 3] * wg[mq * 4 + 3];
        }
        float s = ((s0 + s1) + (s2 + s3)) + wb + xw[n];
        pooled = fmaxf(pooled, s);
    }
    int oidx = ((t * 16 + b) << 9) + o;
    unsigned short h = f2bf(pooled), l = f2bf(pooled - bf2f(h));
    Plh[oidx] = h;
    Pll[oidx] = l;
}

// ---------------------------------------------------------------------------
// out[r] = lrelu( sum_c H[r][c]*p3w[c] + p3b )   one wave per row
// ---------------------------------------------------------------------------
__global__ __launch_bounds__(256) void k_final(const float* __restrict__ H,
                                               const float* __restrict__ p3w,
                                               const float* __restrict__ p3b,
                                               float* __restrict__ out) {
    int r = blockIdx.x * 4 + (threadIdx.x >> 6);
    int lane = threadIdx.x & 63;
    const float4* h4 = (const float4*)&H[r << 9];
    const float4* w4 = (const float4*)p3w;
    float4 a1 = h4[lane], a2 = h4[lane + 64];
    float4 b1 = w4[lane], b2 = w4[lane + 64];
    float s = a1.x * b1.x + a1.y * b1.y + a1.z * b1.z + a1.w * b1.w +
              a2.x * b2.x + a2.y * b2.y + a2.z * b2.z + a2.w * b2.w;
#pragma unroll
    for (int off = 32; off; off >>= 1) s += __shfl_down(s, off, 64);
    if (lane == 0) out[r] = lrelu(s + p3b[0]);
}

extern "C" void kernel_launch(void* const* d_in, const int* in_sizes, int n_in,
                              void* d_out, int out_size, void* d_ws, size_t ws_size,
                              hipStream_t stream) {
    const float* out1 = (const float*)d_in[0];
    const float* out2 = (const float*)d_in[1];
    const float* out3 = (const float*)d_in[2];
    const float* theta_w = (const float*)d_in[3];
    const float* phi_w = (const float*)d_in[4];
    const float* g_w = (const float*)d_in[5];
    const float* W_w = (const float*)d_in[6];
    const float* W_b = (const float*)d_in[7];
    const float* p1_w = (const float*)d_in[8];
    const float* p2_w = (const float*)d_in[9];
    const float* p3_w = (const float*)d_in[10];
    const float* p3_b = (const float*)d_in[11];
    float* outp = (float*)d_out;

    // ---- workspace layout (bytes) ----
    char* wsb = (char*)d_ws;
    unsigned short* Whi = (unsigned short*)(wsb + 0);         // 1024x512 bf16 (Mw | Wg_w)
    unsigned short* Wlo = (unsigned short*)(wsb + 1048576);
    unsigned short* p1h = (unsigned short*)(wsb + 2097152);
    unsigned short* p1l = (unsigned short*)(wsb + 2621440);
    unsigned short* p2h = (unsigned short*)(wsb + 3145728);
    unsigned short* p2l = (unsigned short*)(wsb + 3670016);
    unsigned short* WwH = (unsigned short*)(wsb + 4194304);
    unsigned short* WwL = (unsigned short*)(wsb + 4718592);
    unsigned short* TtH = (unsigned short*)(wsb + 5242880);
    unsigned short* TtL = (unsigned short*)(wsb + 5767168);
    unsigned short* PtH = (unsigned short*)(wsb + 6291456);
    unsigned short* PtL = (unsigned short*)(wsb + 6815744);
    unsigned short* GtH = (unsigned short*)(wsb + 7340032);
    unsigned short* GtL = (unsigned short*)(wsb + 7864320);
    unsigned short* Xh  = (unsigned short*)(wsb + 8388608);   // 6144x512 bf16
    unsigned short* Xl  = (unsigned short*)(wsb + 14680064);
    unsigned short* Yh  = (unsigned short*)(wsb + 20971520);  // 6144x512 bf16
    unsigned short* Yl  = (unsigned short*)(wsb + 27262976);
    float* Wg = (float*)(wsb + 33554432);                     // 6144x512 fp32
    float* D  = (float*)(wsb + 46137344);                     // 144x128x128 fp32
    // aliases (dead-buffer reuse):
    unsigned short* Plh = (unsigned short*)(wsb + 20971520);  // over Yh (dead after gram)
    unsigned short* Pll = (unsigned short*)(wsb + 23068672);
    unsigned short* h1h = (unsigned short*)(wsb + 27262976);  // over Yl (dead after gram)
    unsigned short* h1l = (unsigned short*)(wsb + 29360128);
    float* h2 = (float*)(wsb + 8388608);                      // over Xh (dead after mix)

    // 1. split raw weights: straight (W_w, p1, p2) + transposed (theta, phi, g)
    k_split_w<<<dim3(256, 3), 256, 0, stream>>>(W_w, p1_w, p2_w,
                                                WwH, WwL, p1h, p1l, p2h, p2l);
    k_split_wT<<<dim3(16, 16, 3), dim3(32, 8), 0, stream>>>(theta_w, phi_w, g_w,
                                                            TtH, TtL, PtH, PtL, GtH, GtL);
    // 2. transpose+split inputs (independent of weight GEMMs)
    k_splitx<<<dim3(16, 4, 48), dim3(32, 8), 0, stream>>>(out1, out2, out3, Xh, Xl);
    // 3. weight GEMMs via MFMA: Mw = Tt.Pt^T ; Wg_w = Ww.Gt^T -> Whi/Wlo stacked
    k_wgemm<<<dim3(4, 4, 2), 256, 0, stream>>>(WwH, WwL, GtH, GtL, TtH, TtL,
                                               PtH, PtL, Whi, Wlo);
    // 4. stage A: Y (bf16 hi/lo) + Wg (fp32)
    k_ga<<<dim3(48, 8), 256, 0, stream>>>(Whi, Wlo, Xh, Xl, Yh, Yl, Wg);
    // 5. gram matrices: D = X . Y^T
    k_gram2<<<dim3(144), 256, 0, stream>>>(Xh, Xl, Yh, Yl, D);
    // 6. softmax + mix + residual + pool
    k_mix<<<dim3(2048), 512, 0, stream>>>(Xh, Xl, Wg, D, W_b, Plh, Pll);
    // 7. MLP
    k_mlp<true><<<dim3(16, 4), 256, 0, stream>>>(Plh, Pll, p1h, p1l, h1h, h1l, nullptr);
    k_mlp<false><<<dim3(16, 4), 256, 0, stream>>>(h1h, h1l, p2h, p2l, nullptr, nullptr, h2);
    // 8. final projection
    k_final<<<dim3(512), 256, 0, stream>>>(h2, p3_w, p3_b, outp);
}

// Round 12
// 148.291 us; speedup vs baseline: 1.3266x; 1.0460x over previous
//
#include <hip/hip_runtime.h>

typedef __attribute__((ext_vector_type(8))) short short8;
typedef __attribute__((ext_vector_type(4))) float float4v;
typedef __attribute__((ext_vector_type(4))) unsigned int uint4v;
typedef __attribute__((ext_vector_type(4))) unsigned short ushort4v;

__device__ __forceinline__ float lrelu(float v) { return v >= 0.f ? v : 0.01f * v; }

__device__ __forceinline__ unsigned short f2bf(float x) {
    union { float f; unsigned u; } c; c.f = x;
    unsigned r = (c.u + 0x7FFFu + ((c.u >> 16) & 1u)) >> 16;
    return (unsigned short)r;
}
__device__ __forceinline__ float bf2f(unsigned short h) {
    union { unsigned u; float f; } c; c.u = ((unsigned)h) << 16;
    return c.f;
}

// async global->LDS, 16B per lane. LDS dest must be wave-uniform base
// (HW adds lane*16); global src is per-lane (pre-swizzled).
__device__ __forceinline__ void gload16(const unsigned short* g, unsigned short* l) {
    __builtin_amdgcn_global_load_lds(
        (const __attribute__((address_space(1))) unsigned int*)g,
        (__attribute__((address_space(3))) unsigned int*)l, 16, 0, 0);
}

// ===========================================================================
// Shared MFMA core: C[128x128] += A[128xK] * B[128xK]^T, K=512, split-bf16
// (hi*hi + hi*lo + lo*hi -> ~fp32 precision). 256 threads, 4 waves 2x2.
// LDS: 4 tiles [128][64] bf16. global_load_lds direct staging: LDS linear,
// global source pre-swizzled with the same XOR involution the reads use.
// ===========================================================================
__device__ __forceinline__ void mfma_core(
    const unsigned short* __restrict__ Ah, const unsigned short* __restrict__ Al, int lda,
    const unsigned short* __restrict__ Bh, const unsigned short* __restrict__ Bl, int ldb,
    unsigned short* lds, float4v acc[4][4]) {
    const int tid = threadIdx.x;
    const int lane = tid & 63, wave = tid >> 6;
    const int wm = wave >> 1, wn = wave & 1;
    const int l15 = lane & 15, lhi = lane >> 4;
    unsigned short* LAh = lds;
    unsigned short* LAl = lds + 8192;
    unsigned short* LBh = lds + 16384;
    unsigned short* LBl = lds + 24576;

    for (int k0 = 0; k0 < 512; k0 += 64) {
#pragma unroll
        for (int tile = 0; tile < 4; ++tile) {
            const unsigned short* s = (tile == 0) ? Ah : (tile == 1) ? Al : (tile == 2) ? Bh : Bl;
            int ld = (tile < 2) ? lda : ldb;
            unsigned short* dbase = lds + tile * 8192;
#pragma unroll
            for (int it = 0; it < 4; ++it) {
                int idx = it * 256 + tid;
                int row = idx >> 3, ch = idx & 7;
                // linear LDS dest (wave-uniform base), swizzled global src
                gload16(&s[row * ld + k0 + ((ch ^ (row & 7)) << 3)],
                        dbase + ((it * 256 + wave * 64) << 3));
            }
        }
        __syncthreads();
#pragma unroll
        for (int ks = 0; ks < 2; ++ks) {
            short8 ah[4], al[4], bh[4], bl[4];
#pragma unroll
            for (int m = 0; m < 4; ++m) {
                int r = wm * 64 + m * 16 + l15;
                int off = r * 64 + (((ks * 4 + lhi) ^ (r & 7)) * 8);
                ah[m] = *(const short8*)&LAh[off];
                al[m] = *(const short8*)&LAl[off];
            }
#pragma unroll
            for (int n = 0; n < 4; ++n) {
                int r = wn * 64 + n * 16 + l15;
                int off = r * 64 + (((ks * 4 + lhi) ^ (r & 7)) * 8);
                bh[n] = *(const short8*)&LBh[off];
                bl[n] = *(const short8*)&LBl[off];
            }
#pragma unroll
            for (int m = 0; m < 4; ++m)
#pragma unroll
                for (int n = 0; n < 4; ++n) {
                    acc[m][n] = __builtin_amdgcn_mfma_f32_16x16x32_bf16(ah[m], bh[n], acc[m][n], 0, 0, 0);
                    acc[m][n] = __builtin_amdgcn_mfma_f32_16x16x32_bf16(ah[m], bl[n], acc[m][n], 0, 0, 0);
                    acc[m][n] = __builtin_amdgcn_mfma_f32_16x16x32_bf16(al[m], bh[n], acc[m][n], 0, 0, 0);
                }
        }
        __syncthreads();
    }
}

// ---------------------------------------------------------------------------
// Straight split to bf16 hi/lo: z=0 W_w, z=1 p1_w, z=2 p2_w. grid (256,3).
// ---------------------------------------------------------------------------
__global__ __launch_bounds__(256) void k_split_w(
    const float* __restrict__ ww, const float* __restrict__ p1w,
    const float* __restrict__ p2w, unsigned short* __restrict__ WwH,
    unsigned short* __restrict__ WwL, unsigned short* __restrict__ p1h,
    unsigned short* __restrict__ p1l, unsigned short* __restrict__ p2h,
    unsigned short* __restrict__ p2l) {
    int z = blockIdx.y;
    const float* src = (z == 0) ? ww : (z == 1) ? p1w : p2w;
    unsigned short* dh = (z == 0) ? WwH : (z == 1) ? p1h : p2h;
    unsigned short* dl = (z == 0) ? WwL : (z == 1) ? p1l : p2l;
    int i4 = blockIdx.x * 256 + threadIdx.x;
    float4v v = ((const float4v*)src)[i4];
    ushort4v h, l;
#pragma unroll
    for (int j = 0; j < 4; ++j) {
        h[j] = f2bf(v[j]);
        l[j] = f2bf(v[j] - bf2f(h[j]));
    }
    ((ushort4v*)dh)[i4] = h;
    ((ushort4v*)dl)[i4] = l;
}

// ---------------------------------------------------------------------------
// Transpose+split 512x512 weights: Dst[i][k] = src[k][i] as bf16 hi/lo.
// z=0 theta->Tt, z=1 phi->Pt, z=2 g_w->Gt. grid (16,16,3), block (32,8).
// ---------------------------------------------------------------------------
__global__ __launch_bounds__(256) void k_split_wT(
    const float* __restrict__ tw, const float* __restrict__ fw,
    const float* __restrict__ gw, unsigned short* __restrict__ TtH,
    unsigned short* __restrict__ TtL, unsigned short* __restrict__ PtH,
    unsigned short* __restrict__ PtL, unsigned short* __restrict__ GtH,
    unsigned short* __restrict__ GtL) {
    int z = blockIdx.z;
    const float* src = (z == 0) ? tw : (z == 1) ? fw : gw;
    unsigned short* dh = (z == 0) ? TtH : (z == 1) ? PtH : GtH;
    unsigned short* dl = (z == 0) ? TtL : (z == 1) ? PtL : GtL;
    int i0 = blockIdx.x * 32, k0 = blockIdx.y * 32;
    __shared__ float tile[32][33];
    int tx = threadIdx.x, ty = threadIdx.y;
#pragma unroll
    for (int i = 0; i < 4; ++i)
        tile[ty + i * 8][tx] = src[(k0 + ty + i * 8) * 512 + i0 + tx];
    __syncthreads();
#pragma unroll
    for (int i = 0; i < 4; ++i) {
        int row = i0 + ty + i * 8;
        float v = tile[tx][ty + i * 8];  // = src[k0+tx][row]
        unsigned short h = f2bf(v), l = f2bf(v - bf2f(h));
        int idx = row * 512 + k0 + tx;
        dh[idx] = h;
        dl[idx] = l;
    }
}

// ---------------------------------------------------------------------------
// Weight GEMMs via MFMA, epilogue splits into stacked Whi/Wlo [1024][512]:
//   z=1: Mw   = Tt . Pt^T -> rows 0-511    (Mw[i][j] = sum_k theta[k][i] phi[k][j])
//   z=0: Wg_w = Ww . Gt^T -> rows 512-1023 (Wg_w[i][j] = sum_k W_w[i][k] g_w[k][j])
// grid (4,4,2), block 256.
// ---------------------------------------------------------------------------
__global__ __launch_bounds__(256) void k_wgemm(
    const unsigned short* __restrict__ WwH, const unsigned short* __restrict__ WwL,
    const unsigned short* __restrict__ GtH, const unsigned short* __restrict__ GtL,
    const unsigned short* __restrict__ TtH, const unsigned short* __restrict__ TtL,
    const unsigned short* __restrict__ PtH, const unsigned short* __restrict__ PtL,
    unsigned short* __restrict__ Whi, unsigned short* __restrict__ Wlo) {
    __shared__ unsigned short lds[32768];
    int i0 = blockIdx.y * 128, j0 = blockIdx.x * 128;
    bool wg = blockIdx.z == 0;
    const unsigned short* Ah = (wg ? WwH : TtH) + i0 * 512;
    const unsigned short* Al = (wg ? WwL : TtL) + i0 * 512;
    const unsigned short* Bh = (wg ? GtH : PtH) + j0 * 512;
    const unsigned short* Bl = (wg ? GtL : PtL) + j0 * 512;
    float4v acc[4][4];
#pragma unroll
    for (int m = 0; m < 4; ++m)
#pragma unroll
        for (int n = 0; n < 4; ++n) acc[m][n] = (float4v){0.f, 0.f, 0.f, 0.f};

    mfma_core(Ah, Al, 512, Bh, Bl, 512, lds, acc);

    int lane = threadIdx.x & 63, wave = threadIdx.x >> 6;
    int wm = wave >> 1, wn = wave & 1, l15 = lane & 15, lhi = lane >> 4;
    int rowbase = wg ? 512 + i0 : i0;
#pragma unroll
    for (int m = 0; m < 4; ++m)
#pragma unroll
        for (int n = 0; n < 4; ++n) {
            int bcol = j0 + wn * 64 + n * 16 + l15;
#pragma unroll
            for (int i = 0; i < 4; ++i) {
                int r = rowbase + wm * 64 + m * 16 + lhi * 4 + i;
                float v = acc[m][n][i];
                unsigned short h = f2bf(v), l = f2bf(v - bf2f(h));
                Whi[r * 512 + bcol] = h;
                Wlo[r * 512 + bcol] = l;
            }
        }
}

// ---------------------------------------------------------------------------
// Transpose+split inputs: Xt[((b*128+t)*3+k)*512 + c] = in_k[b][c][t] (hi/lo)
// ---------------------------------------------------------------------------
__global__ __launch_bounds__(256) void k_splitx(const float* __restrict__ o1,
                                                const float* __restrict__ o2,
                                                const float* __restrict__ o3,
                                                unsigned short* __restrict__ Xh,
                                                unsigned short* __restrict__ Xl) {
    int z = blockIdx.z;
    int b = z / 3, k = z - b * 3;
    const float* In = (k == 0) ? o1 : ((k == 1) ? o2 : o3);
    int c0 = blockIdx.x * 32, t0 = blockIdx.y * 32;
    __shared__ float tile[32][33];
    int tx = threadIdx.x, ty = threadIdx.y;
#pragma unroll
    for (int i = 0; i < 4; ++i)
        tile[ty + i * 8][tx] = In[(b * 512 + c0 + ty + i * 8) * 128 + t0 + tx];
    __syncthreads();
#pragma unroll
    for (int i = 0; i < 4; ++i) {
        int t = t0 + ty + i * 8;
        float v = tile[tx][ty + i * 8];
        unsigned short h = f2bf(v), l = f2bf(v - bf2f(h));
        int idx = ((b * 128 + t) * 3 + k) * 512 + c0 + tx;
        Xh[idx] = h;
        Xl[idx] = l;
    }
}

// ---------------------------------------------------------------------------
// Stage A via MFMA: grid (48, 8): x = b*3+kin, y = o-tile
//   y 0-3 -> Y = Mw . x (bf16 hi/lo), y 4-7 -> Wg = Wg_w . x (fp32)
// ---------------------------------------------------------------------------
__global__ __launch_bounds__(256) void k_ga(
    const unsigned short* __restrict__ Whi, const unsigned short* __restrict__ Wlo,
    const unsigned short* __restrict__ Xh, const unsigned short* __restrict__ Xl,
    unsigned short* __restrict__ Yh, unsigned short* __restrict__ Yl,
    float* __restrict__ Wg) {
    __shared__ unsigned short lds[32768];
    int bk = blockIdx.x, y = blockIdx.y;
    int b = bk / 3, kin = bk - b * 3;
    int bbase = (b * 384 + kin) * 512;
    float4v acc[4][4];
#pragma unroll
    for (int m = 0; m < 4; ++m)
#pragma unroll
        for (int n = 0; n < 4; ++n) acc[m][n] = (float4v){0.f, 0.f, 0.f, 0.f};

    mfma_core(Whi + y * 128 * 512, Wlo + y * 128 * 512, 512,
              Xh + bbase, Xl + bbase, 1536, lds, acc);

    int lane = threadIdx.x & 63, wave = threadIdx.x >> 6;
    int wm = wave >> 1, wn = wave & 1, l15 = lane & 15, lhi = lane >> 4;
    int wsel = y >> 2, o0 = (y & 3) * 128;
#pragma unroll
    for (int m = 0; m < 4; ++m)
#pragma unroll
        for (int n = 0; n < 4; ++n) {
            int o_in = wm * 64 + m * 16 + lhi * 4;
            int t = wn * 64 + n * 16 + l15;
            int idx = bbase + t * 1536 + o0 + o_in;
            if (wsel == 1) {
                *(float4v*)&Wg[idx] = acc[m][n];
            } else {
                ushort4v h, l;
#pragma unroll
                for (int i = 0; i < 4; ++i) {
                    float v = acc[m][n][i];
                    h[i] = f2bf(v);
                    l[i] = f2bf(v - bf2f(h[i]));
                }
                *(ushort4v*)&Yh[idx] = h;
                *(ushort4v*)&Yl[idx] = l;
            }
        }
}

// ---------------------------------------------------------------------------
// Gram via MFMA: D[mat][t1][t2] = X[b,t1,k,:] . Y[b,t2,kp,:]
// grid 144, XCD-swizzled so same-b mats share an XCD's L2.
// ---------------------------------------------------------------------------
__global__ __launch_bounds__(256) void k_gram2(
    const unsigned short* __restrict__ Xh, const unsigned short* __restrict__ Xl,
    const unsigned short* __restrict__ Yh, const unsigned short* __restrict__ Yl,
    float* __restrict__ D) {
    __shared__ unsigned short lds[32768];
    int orig = blockIdx.x;
    int mat = (orig & 7) * 18 + (orig >> 3);  // 144 = 8 * 18, bijective
    int b = mat / 9, r9 = mat - b * 9, k = r9 / 3, kp = r9 - k * 3;
    int Ab = (b * 384 + k) * 512, Bb = (b * 384 + kp) * 512;
    float4v acc[4][4];
#pragma unroll
    for (int m = 0; m < 4; ++m)
#pragma unroll
        for (int n = 0; n < 4; ++n) acc[m][n] = (float4v){0.f, 0.f, 0.f, 0.f};

    mfma_core(Xh + Ab, Xl + Ab, 1536, Yh + Bb, Yl + Bb, 1536, lds, acc);

    int lane = threadIdx.x & 63, wave = threadIdx.x >> 6;
    int wm = wave >> 1, wn = wave & 1, l15 = lane & 15, lhi = lane >> 4;
    float* Dm = D + mat * 16384;
#pragma unroll
    for (int m = 0; m < 4; ++m)
#pragma unroll
        for (int n = 0; n < 4; ++n) {
            int t2 = wn * 64 + n * 16 + l15;
#pragma unroll
            for (int i = 0; i < 4; ++i) {
                int t1 = wm * 64 + m * 16 + lhi * 4 + i;
                Dm[t1 * 128 + t2] = acc[m][n][i];
            }
        }
}

// ---------------------------------------------------------------------------
// MLP layer via MFMA: C[r][o] = lrelu( A[r,:] . W[o,:] )
// ---------------------------------------------------------------------------
template <bool SPLIT_OUT>
__global__ __launch_bounds__(256) void k_mlp(
    const unsigned short* __restrict__ Ahi, const unsigned short* __restrict__ Alo,
    const unsigned short* __restrict__ Bhi, const unsigned short* __restrict__ Blo,
    unsigned short* __restrict__ Ch, unsigned short* __restrict__ Cl,
    float* __restrict__ Cf) {
    __shared__ unsigned short lds[32768];
    int r0 = blockIdx.x * 128, o0 = blockIdx.y * 128;
    float4v acc[4][4];
#pragma unroll
    for (int m = 0; m < 4; ++m)
#pragma unroll
        for (int n = 0; n < 4; ++n) acc[m][n] = (float4v){0.f, 0.f, 0.f, 0.f};

    mfma_core(Ahi + r0 * 512, Alo + r0 * 512, 512, Bhi + o0 * 512, Blo + o0 * 512, 512, lds, acc);

    int lane = threadIdx.x & 63, wave = threadIdx.x >> 6;
    int wm = wave >> 1, wn = wave & 1, l15 = lane & 15, lhi = lane >> 4;
#pragma unroll
    for (int m = 0; m < 4; ++m)
#pragma unroll
        for (int n = 0; n < 4; ++n) {
            int o = o0 + wn * 64 + n * 16 + l15;
#pragma unroll
            for (int i = 0; i < 4; ++i) {
                int r = r0 + wm * 64 + m * 16 + lhi * 4 + i;
                float v = lrelu(acc[m][n][i]);
                if (SPLIT_OUT) {
                    unsigned short h = f2bf(v), l = f2bf(v - bf2f(h));
                    Ch[r * 512 + o] = h;
                    Cl[r * 512 + o] = l;
                } else {
                    Cf[r * 512 + o] = v;
                }
            }
        }
}

// ---------------------------------------------------------------------------
// Mix, 4 t's per block (r12): amortize preload/softmax/gather across
// adjacent t's whose windows overlap 7/8. grid 512 (b,tgroup) XCD-swizzled,
// block 512, one o per thread. Preload = union window, 11 slots x 3 k.
// Inner math bit-identical to r8 body per t (slot offset dt*3).
// ---------------------------------------------------------------------------
__global__ __launch_bounds__(512) void k_mix(
    const unsigned short* __restrict__ Xh, const unsigned short* __restrict__ Xl,
    const float* __restrict__ Wg, const float* __restrict__ D,
    const float* __restrict__ W_b, unsigned short* __restrict__ Plh,
    unsigned short* __restrict__ Pll) {
    int orig = blockIdx.x;
    int bid = ((orig & 7) << 6) | (orig >> 3);  // 512 = 8 * 64, bijective
    int b = bid >> 5, tg = bid & 31;
    int t0 = tg * 4;
    int tid = threadIdx.x;

    __shared__ float Pm[4][24][28];

    // gather f for 4 t's
    for (int idx = tid; idx < 4 * 576; idx += 512) {
        int dt = idx / 576, r = idx - dt * 576;
        int n = r / 24, m = r - n * 24;
        int t = t0 + dt;
        int j = n / 3, k = n - j * 3;
        int jp = m / 3, kp = m - jp * 3;
        int t1 = t - 7 + j, t2 = t - 7 + jp;
        float v = 0.f;
        if (t1 >= 0 && t2 >= 0)
            v = D[((((b * 3 + k) * 3 + kp) * 128 + t1) << 7) + t2];
        Pm[dt][n][m] = v;
    }
    __syncthreads();

    // softmax: 96 rows in parallel
    if (tid < 96) {
        int dt = tid / 24, n = tid - dt * 24;
        float mx = -1e30f;
#pragma unroll
        for (int m = 0; m < 24; ++m) mx = fmaxf(mx, Pm[dt][n][m]);
        float e[24], sum = 0.f;
#pragma unroll
        for (int m = 0; m < 24; ++m) { e[m] = __expf(Pm[dt][n][m] - mx); sum += e[m]; }
        float inv = 1.0f / sum;
#pragma unroll
        for (int m = 0; m < 24; ++m) Pm[dt][n][m] = e[m] * inv;
    }
    __syncthreads();

    int o = tid;
    // union preload: slot s <-> tp = t0 - 7 + s, s in [0, 10], x3 k
    float wg[33], xw[33];
#pragma unroll
    for (int s = 0; s < 11; ++s) {
        int tp = t0 - 7 + s;
#pragma unroll
        for (int k = 0; k < 3; ++k) {
            int base = (((b * 128 + tp) * 3 + k) << 9) + o;
            bool ok = (tp >= 0);
            wg[s * 3 + k] = ok ? Wg[base] : 0.f;
            xw[s * 3 + k] = ok ? (bf2f(Xh[base]) + bf2f(Xl[base])) : 0.f;
        }
    }
    float wb = W_b[o];
#pragma unroll
    for (int dt = 0; dt < 4; ++dt) {
        float pooled = -1e30f;
#pragma unroll
        for (int n = 0; n < 24; ++n) {
            float s0 = 0.f, s1 = 0.f, s2 = 0.f, s3 = 0.f;
#pragma unroll
            for (int mq = 0; mq < 6; ++mq) {
                s0 += Pm[dt][n][mq * 4 + 0] * wg[mq * 4 + 0 + dt * 3];
                s1 += Pm[dt][n][mq * 4 + 1] * wg[mq * 4 + 1 + dt * 3];
                s2 += Pm[dt][n][mq * 4 + 2] * wg[mq * 4 + 2 + dt * 3];
                s3 += Pm[dt][n][mq * 4 + 3] * wg[mq * 4 + 3 + dt * 3];
            }
            float s = ((s0 + s1) + (s2 + s3)) + wb + xw[n + dt * 3];
            pooled = fmaxf(pooled, s);
        }
        int t = t0 + dt;
        int oidx = ((t * 16 + b) << 9) + o;
        unsigned short h = f2bf(pooled), l = f2bf(pooled - bf2f(h));
        Plh[oidx] = h;
        Pll[oidx] = l;
    }
}

// ---------------------------------------------------------------------------
// out[r] = lrelu( sum_c H[r][c]*p3w[c] + p3b )   one wave per row
// ---------------------------------------------------------------------------
__global__ __launch_bounds__(256) void k_final(const float* __restrict__ H,
                                               const float* __restrict__ p3w,
                                               const float* __restrict__ p3b,
                                               float* __restrict__ out) {
    int r = blockIdx.x * 4 + (threadIdx.x >> 6);
    int lane = threadIdx.x & 63;
    const float4* h4 = (const float4*)&H[r << 9];
    const float4* w4 = (const float4*)p3w;
    float4 a1 = h4[lane], a2 = h4[lane + 64];
    float4 b1 = w4[lane], b2 = w4[lane + 64];
    float s = a1.x * b1.x + a1.y * b1.y + a1.z * b1.z + a1.w * b1.w +
              a2.x * b2.x + a2.y * b2.y + a2.z * b2.z + a2.w * b2.w;
#pragma unroll
    for (int off = 32; off; off >>= 1) s += __shfl_down(s, off, 64);
    if (lane == 0) out[r] = lrelu(s + p3b[0]);
}

extern "C" void kernel_launch(void* const* d_in, const int* in_sizes, int n_in,
                              void* d_out, int out_size, void* d_ws, size_t ws_size,
                              hipStream_t stream) {
    const float* out1 = (const float*)d_in[0];
    const float* out2 = (const float*)d_in[1];
    const float* out3 = (const float*)d_in[2];
    const float* theta_w = (const float*)d_in[3];
    const float* phi_w = (const float*)d_in[4];
    const float* g_w = (const float*)d_in[5];
    const float* W_w = (const float*)d_in[6];
    const float* W_b = (const float*)d_in[7];
    const float* p1_w = (const float*)d_in[8];
    const float* p2_w = (const float*)d_in[9];
    const float* p3_w = (const float*)d_in[10];
    const float* p3_b = (const float*)d_in[11];
    float* outp = (float*)d_out;

    // ---- workspace layout (bytes) ----
    char* wsb = (char*)d_ws;
    unsigned short* Whi = (unsigned short*)(wsb + 0);         // 1024x512 bf16 (Mw | Wg_w)
    unsigned short* Wlo = (unsigned short*)(wsb + 1048576);
    unsigned short* p1h = (unsigned short*)(wsb + 2097152);
    unsigned short* p1l = (unsigned short*)(wsb + 2621440);
    unsigned short* p2h = (unsigned short*)(wsb + 3145728);
    unsigned short* p2l = (unsigned short*)(wsb + 3670016);
    unsigned short* WwH = (unsigned short*)(wsb + 4194304);
    unsigned short* WwL = (unsigned short*)(wsb + 4718592);
    unsigned short* TtH = (unsigned short*)(wsb + 5242880);
    unsigned short* TtL = (unsigned short*)(wsb + 5767168);
    unsigned short* PtH = (unsigned short*)(wsb + 6291456);
    unsigned short* PtL = (unsigned short*)(wsb + 6815744);
    unsigned short* GtH = (unsigned short*)(wsb + 7340032);
    unsigned short* GtL = (unsigned short*)(wsb + 7864320);
    unsigned short* Xh  = (unsigned short*)(wsb + 8388608);   // 6144x512 bf16
    unsigned short* Xl  = (unsigned short*)(wsb + 14680064);
    unsigned short* Yh  = (unsigned short*)(wsb + 20971520);  // 6144x512 bf16
    unsigned short* Yl  = (unsigned short*)(wsb + 27262976);
    float* Wg = (float*)(wsb + 33554432);                     // 6144x512 fp32
    float* D  = (float*)(wsb + 46137344);                     // 144x128x128 fp32
    // aliases (dead-buffer reuse):
    unsigned short* Plh = (unsigned short*)(wsb + 20971520);  // over Yh (dead after gram)
    unsigned short* Pll = (unsigned short*)(wsb + 23068672);
    unsigned short* h1h = (unsigned short*)(wsb + 27262976);  // over Yl (dead after gram)
    unsigned short* h1l = (unsigned short*)(wsb + 29360128);
    float* h2 = (float*)(wsb + 8388608);                      // over Xh (dead after mix)

    // 1. split raw weights: straight (W_w, p1, p2) + transposed (theta, phi, g)
    k_split_w<<<dim3(256, 3), 256, 0, stream>>>(W_w, p1_w, p2_w,
                                                WwH, WwL, p1h, p1l, p2h, p2l);
    k_split_wT<<<dim3(16, 16, 3), dim3(32, 8), 0, stream>>>(theta_w, phi_w, g_w,
                                                            TtH, TtL, PtH, PtL, GtH, GtL);
    // 2. transpose+split inputs (independent of weight GEMMs)
    k_splitx<<<dim3(16, 4, 48), dim3(32, 8), 0, stream>>>(out1, out2, out3, Xh, Xl);
    // 3. weight GEMMs via MFMA: Mw = Tt.Pt^T ; Wg_w = Ww.Gt^T -> Whi/Wlo stacked
    k_wgemm<<<dim3(4, 4, 2), 256, 0, stream>>>(WwH, WwL, GtH, GtL, TtH, TtL,
                                               PtH, PtL, Whi, Wlo);
    // 4. stage A: Y (bf16 hi/lo) + Wg (fp32)
    k_ga<<<dim3(48, 8), 256, 0, stream>>>(Whi, Wlo, Xh, Xl, Yh, Yl, Wg);
    // 5. gram matrices: D = X . Y^T
    k_gram2<<<dim3(144), 256, 0, stream>>>(Xh, Xl, Yh, Yl, D);
    // 6. softmax + mix + residual + pool (4 t's per block)
    k_mix<<<dim3(512), 512, 0, stream>>>(Xh, Xl, Wg, D, W_b, Plh, Pll);
    // 7. MLP
    k_mlp<true><<<dim3(16, 4), 256, 0, stream>>>(Plh, Pll, p1h, p1l, h1h, h1l, nullptr);
    k_mlp<false><<<dim3(16, 4), 256, 0, stream>>>(h1h, h1l, p2h, p2l, nullptr, nullptr, h2);
    // 8. final projection
    k_final<<<dim3(512), 256, 0, stream>>>(h2, p3_w, p3_b, outp);
}

// Round 13
// 139.161 us; speedup vs baseline: 1.4136x; 1.0656x over previous
//
#include <hip/hip_runtime.h>

typedef __attribute__((ext_vector_type(8))) short short8;
typedef __attribute__((ext_vector_type(4))) float float4v;
typedef __attribute__((ext_vector_type(4))) unsigned int uint4v;
typedef __attribute__((ext_vector_type(4))) unsigned short ushort4v;

__device__ __forceinline__ float lrelu(float v) { return v >= 0.f ? v : 0.01f * v; }

__device__ __forceinline__ unsigned short f2bf(float x) {
    union { float f; unsigned u; } c; c.f = x;
    unsigned r = (c.u + 0x7FFFu + ((c.u >> 16) & 1u)) >> 16;
    return (unsigned short)r;
}
__device__ __forceinline__ float bf2f(unsigned short h) {
    union { unsigned u; float f; } c; c.u = ((unsigned)h) << 16;
    return c.f;
}

// async global->LDS, 16B per lane. LDS dest must be wave-uniform base
// (HW adds lane*16); global src is per-lane (pre-swizzled).
__device__ __forceinline__ void gload16(const unsigned short* g, unsigned short* l) {
    __builtin_amdgcn_global_load_lds(
        (const __attribute__((address_space(1))) unsigned int*)g,
        (__attribute__((address_space(3))) unsigned int*)l, 16, 0, 0);
}

// ===========================================================================
// Shared MFMA core: C[128x128] += A[128xK] * B[128xK]^T, K=512, split-bf16
// (hi*hi + hi*lo + lo*hi -> ~fp32 precision). 256 threads, 4 waves 2x2.
// LDS: 4 tiles [128][64] bf16. global_load_lds direct staging: LDS linear,
// global source pre-swizzled with the same XOR involution the reads use.
// ===========================================================================
__device__ __forceinline__ void mfma_core(
    const unsigned short* __restrict__ Ah, const unsigned short* __restrict__ Al, int lda,
    const unsigned short* __restrict__ Bh, const unsigned short* __restrict__ Bl, int ldb,
    unsigned short* lds, float4v acc[4][4]) {
    const int tid = threadIdx.x;
    const int lane = tid & 63, wave = tid >> 6;
    const int wm = wave >> 1, wn = wave & 1;
    const int l15 = lane & 15, lhi = lane >> 4;
    unsigned short* LAh = lds;
    unsigned short* LAl = lds + 8192;
    unsigned short* LBh = lds + 16384;
    unsigned short* LBl = lds + 24576;

    for (int k0 = 0; k0 < 512; k0 += 64) {
#pragma unroll
        for (int tile = 0; tile < 4; ++tile) {
            const unsigned short* s = (tile == 0) ? Ah : (tile == 1) ? Al : (tile == 2) ? Bh : Bl;
            int ld = (tile < 2) ? lda : ldb;
            unsigned short* dbase = lds + tile * 8192;
#pragma unroll
            for (int it = 0; it < 4; ++it) {
                int idx = it * 256 + tid;
                int row = idx >> 3, ch = idx & 7;
                // linear LDS dest (wave-uniform base), swizzled global src
                gload16(&s[row * ld + k0 + ((ch ^ (row & 7)) << 3)],
                        dbase + ((it * 256 + wave * 64) << 3));
            }
        }
        __syncthreads();
#pragma unroll
        for (int ks = 0; ks < 2; ++ks) {
            short8 ah[4], al[4], bh[4], bl[4];
#pragma unroll
            for (int m = 0; m < 4; ++m) {
                int r = wm * 64 + m * 16 + l15;
                int off = r * 64 + (((ks * 4 + lhi) ^ (r & 7)) * 8);
                ah[m] = *(const short8*)&LAh[off];
                al[m] = *(const short8*)&LAl[off];
            }
#pragma unroll
            for (int n = 0; n < 4; ++n) {
                int r = wn * 64 + n * 16 + l15;
                int off = r * 64 + (((ks * 4 + lhi) ^ (r & 7)) * 8);
                bh[n] = *(const short8*)&LBh[off];
                bl[n] = *(const short8*)&LBl[off];
            }
#pragma unroll
            for (int m = 0; m < 4; ++m)
#pragma unroll
                for (int n = 0; n < 4; ++n) {
                    acc[m][n] = __builtin_amdgcn_mfma_f32_16x16x32_bf16(ah[m], bh[n], acc[m][n], 0, 0, 0);
                    acc[m][n] = __builtin_amdgcn_mfma_f32_16x16x32_bf16(ah[m], bl[n], acc[m][n], 0, 0, 0);
                    acc[m][n] = __builtin_amdgcn_mfma_f32_16x16x32_bf16(al[m], bh[n], acc[m][n], 0, 0, 0);
                }
        }
        __syncthreads();
    }
}

// ---------------------------------------------------------------------------
// Straight split to bf16 hi/lo: z=0 W_w, z=1 p1_w, z=2 p2_w. grid (256,3).
// ---------------------------------------------------------------------------
__global__ __launch_bounds__(256) void k_split_w(
    const float* __restrict__ ww, const float* __restrict__ p1w,
    const float* __restrict__ p2w, unsigned short* __restrict__ WwH,
    unsigned short* __restrict__ WwL, unsigned short* __restrict__ p1h,
    unsigned short* __restrict__ p1l, unsigned short* __restrict__ p2h,
    unsigned short* __restrict__ p2l) {
    int z = blockIdx.y;
    const float* src = (z == 0) ? ww : (z == 1) ? p1w : p2w;
    unsigned short* dh = (z == 0) ? WwH : (z == 1) ? p1h : p2h;
    unsigned short* dl = (z == 0) ? WwL : (z == 1) ? p1l : p2l;
    int i4 = blockIdx.x * 256 + threadIdx.x;
    float4v v = ((const float4v*)src)[i4];
    ushort4v h, l;
#pragma unroll
    for (int j = 0; j < 4; ++j) {
        h[j] = f2bf(v[j]);
        l[j] = f2bf(v[j] - bf2f(h[j]));
    }
    ((ushort4v*)dh)[i4] = h;
    ((ushort4v*)dl)[i4] = l;
}

// ---------------------------------------------------------------------------
// Transpose+split 512x512 weights: Dst[i][k] = src[k][i] as bf16 hi/lo.
// z=0 theta->Tt, z=1 phi->Pt, z=2 g_w->Gt. grid (16,16,3), block (32,8).
// ---------------------------------------------------------------------------
__global__ __launch_bounds__(256) void k_split_wT(
    const float* __restrict__ tw, const float* __restrict__ fw,
    const float* __restrict__ gw, unsigned short* __restrict__ TtH,
    unsigned short* __restrict__ TtL, unsigned short* __restrict__ PtH,
    unsigned short* __restrict__ PtL, unsigned short* __restrict__ GtH,
    unsigned short* __restrict__ GtL) {
    int z = blockIdx.z;
    const float* src = (z == 0) ? tw : (z == 1) ? fw : gw;
    unsigned short* dh = (z == 0) ? TtH : (z == 1) ? PtH : GtH;
    unsigned short* dl = (z == 0) ? TtL : (z == 1) ? PtL : GtL;
    int i0 = blockIdx.x * 32, k0 = blockIdx.y * 32;
    __shared__ float tile[32][33];
    int tx = threadIdx.x, ty = threadIdx.y;
#pragma unroll
    for (int i = 0; i < 4; ++i)
        tile[ty + i * 8][tx] = src[(k0 + ty + i * 8) * 512 + i0 + tx];
    __syncthreads();
#pragma unroll
    for (int i = 0; i < 4; ++i) {
        int row = i0 + ty + i * 8;
        float v = tile[tx][ty + i * 8];  // = src[k0+tx][row]
        unsigned short h = f2bf(v), l = f2bf(v - bf2f(h));
        int idx = row * 512 + k0 + tx;
        dh[idx] = h;
        dl[idx] = l;
    }
}

// ---------------------------------------------------------------------------
// Weight GEMMs via MFMA, epilogue splits into stacked Whi/Wlo [1024][512]:
//   z=1: Mw   = Tt . Pt^T -> rows 0-511    (Mw[i][j] = sum_k theta[k][i] phi[k][j])
//   z=0: Wg_w = Ww . Gt^T -> rows 512-1023 (Wg_w[i][j] = sum_k W_w[i][k] g_w[k][j])
// grid (4,4,2), block 256.
// ---------------------------------------------------------------------------
__global__ __launch_bounds__(256) void k_wgemm(
    const unsigned short* __restrict__ WwH, const unsigned short* __restrict__ WwL,
    const unsigned short* __restrict__ GtH, const unsigned short* __restrict__ GtL,
    const unsigned short* __restrict__ TtH, const unsigned short* __restrict__ TtL,
    const unsigned short* __restrict__ PtH, const unsigned short* __restrict__ PtL,
    unsigned short* __restrict__ Whi, unsigned short* __restrict__ Wlo) {
    __shared__ unsigned short lds[32768];
    int i0 = blockIdx.y * 128, j0 = blockIdx.x * 128;
    bool wg = blockIdx.z == 0;
    const unsigned short* Ah = (wg ? WwH : TtH) + i0 * 512;
    const unsigned short* Al = (wg ? WwL : TtL) + i0 * 512;
    const unsigned short* Bh = (wg ? GtH : PtH) + j0 * 512;
    const unsigned short* Bl = (wg ? GtL : PtL) + j0 * 512;
    float4v acc[4][4];
#pragma unroll
    for (int m = 0; m < 4; ++m)
#pragma unroll
        for (int n = 0; n < 4; ++n) acc[m][n] = (float4v){0.f, 0.f, 0.f, 0.f};

    mfma_core(Ah, Al, 512, Bh, Bl, 512, lds, acc);

    int lane = threadIdx.x & 63, wave = threadIdx.x >> 6;
    int wm = wave >> 1, wn = wave & 1, l15 = lane & 15, lhi = lane >> 4;
    int rowbase = wg ? 512 + i0 : i0;
#pragma unroll
    for (int m = 0; m < 4; ++m)
#pragma unroll
        for (int n = 0; n < 4; ++n) {
            int bcol = j0 + wn * 64 + n * 16 + l15;
#pragma unroll
            for (int i = 0; i < 4; ++i) {
                int r = rowbase + wm * 64 + m * 16 + lhi * 4 + i;
                float v = acc[m][n][i];
                unsigned short h = f2bf(v), l = f2bf(v - bf2f(h));
                Whi[r * 512 + bcol] = h;
                Wlo[r * 512 + bcol] = l;
            }
        }
}

// ---------------------------------------------------------------------------
// Transpose+split inputs: Xt[((b*128+t)*3+k)*512 + c] = in_k[b][c][t] (hi/lo)
// ---------------------------------------------------------------------------
__global__ __launch_bounds__(256) void k_splitx(const float* __restrict__ o1,
                                                const float* __restrict__ o2,
                                                const float* __restrict__ o3,
                                                unsigned short* __restrict__ Xh,
                                                unsigned short* __restrict__ Xl) {
    int z = blockIdx.z;
    int b = z / 3, k = z - b * 3;
    const float* In = (k == 0) ? o1 : ((k == 1) ? o2 : o3);
    int c0 = blockIdx.x * 32, t0 = blockIdx.y * 32;
    __shared__ float tile[32][33];
    int tx = threadIdx.x, ty = threadIdx.y;
#pragma unroll
    for (int i = 0; i < 4; ++i)
        tile[ty + i * 8][tx] = In[(b * 512 + c0 + ty + i * 8) * 128 + t0 + tx];
    __syncthreads();
#pragma unroll
    for (int i = 0; i < 4; ++i) {
        int t = t0 + ty + i * 8;
        float v = tile[tx][ty + i * 8];
        unsigned short h = f2bf(v), l = f2bf(v - bf2f(h));
        int idx = ((b * 128 + t) * 3 + k) * 512 + c0 + tx;
        Xh[idx] = h;
        Xl[idx] = l;
    }
}

// ---------------------------------------------------------------------------
// Stage A via MFMA: grid (48, 8): x = b*3+kin, y = o-tile
//   y 0-3 -> Y = Mw . x (bf16 hi/lo), y 4-7 -> Wg = Wg_w . x (fp32)
// ---------------------------------------------------------------------------
__global__ __launch_bounds__(256) void k_ga(
    const unsigned short* __restrict__ Whi, const unsigned short* __restrict__ Wlo,
    const unsigned short* __restrict__ Xh, const unsigned short* __restrict__ Xl,
    unsigned short* __restrict__ Yh, unsigned short* __restrict__ Yl,
    float* __restrict__ Wg) {
    __shared__ unsigned short lds[32768];
    int bk = blockIdx.x, y = blockIdx.y;
    int b = bk / 3, kin = bk - b * 3;
    int bbase = (b * 384 + kin) * 512;
    float4v acc[4][4];
#pragma unroll
    for (int m = 0; m < 4; ++m)
#pragma unroll
        for (int n = 0; n < 4; ++n) acc[m][n] = (float4v){0.f, 0.f, 0.f, 0.f};

    mfma_core(Whi + y * 128 * 512, Wlo + y * 128 * 512, 512,
              Xh + bbase, Xl + bbase, 1536, lds, acc);

    int lane = threadIdx.x & 63, wave = threadIdx.x >> 6;
    int wm = wave >> 1, wn = wave & 1, l15 = lane & 15, lhi = lane >> 4;
    int wsel = y >> 2, o0 = (y & 3) * 128;
#pragma unroll
    for (int m = 0; m < 4; ++m)
#pragma unroll
        for (int n = 0; n < 4; ++n) {
            int o_in = wm * 64 + m * 16 + lhi * 4;
            int t = wn * 64 + n * 16 + l15;
            int idx = bbase + t * 1536 + o0 + o_in;
            if (wsel == 1) {
                *(float4v*)&Wg[idx] = acc[m][n];
            } else {
                ushort4v h, l;
#pragma unroll
                for (int i = 0; i < 4; ++i) {
                    float v = acc[m][n][i];
                    h[i] = f2bf(v);
                    l[i] = f2bf(v - bf2f(h[i]));
                }
                *(ushort4v*)&Yh[idx] = h;
                *(ushort4v*)&Yl[idx] = l;
            }
        }
}

// ---------------------------------------------------------------------------
// Band gram (r13): k_mix only reads |t1-t2|<=7, so compute only the band.
// grid 1152 = (mat, t1-chunk c) XCD-swizzled, block 64 (1 wave).
// Per block: A = X rows [16c,16c+16), B = Y rows [16c-16,16c+32) (clamped),
// 3 output tiles 16x16 (t2 chunks c-1,c,c+1; OOB tiles computed on clamped
// rows but never written). Same swizzled gload16 staging as mfma_core.
// ---------------------------------------------------------------------------
__global__ __launch_bounds__(64) void k_gram3(
    const unsigned short* __restrict__ Xh, const unsigned short* __restrict__ Xl,
    const unsigned short* __restrict__ Yh, const unsigned short* __restrict__ Yl,
    float* __restrict__ D) {
    __shared__ unsigned short lds[8192];  // Ah[16][64] Al[16][64] Bh[48][64] Bl[48][64]
    int orig = blockIdx.x;
    int idx = (orig & 7) * 144 + (orig >> 3);  // 1152 = 8*144, bijective
    int mat = idx >> 3, c = idx & 7;
    int b = mat / 9, r9 = mat - b * 9, k = r9 / 3, kp = r9 - k * 3;
    const unsigned short* Ahg = Xh + (b * 384 + k) * 512;
    const unsigned short* Alg = Xl + (b * 384 + k) * 512;
    const unsigned short* Bhg = Yh + (b * 384 + kp) * 512;
    const unsigned short* Blg = Yl + (b * 384 + kp) * 512;
    int t1b = c * 16, t2b0 = c * 16 - 16;
    unsigned short* LAh = lds;          // [16][64]
    unsigned short* LAl = lds + 1024;
    unsigned short* LBh = lds + 2048;   // [48][64]
    unsigned short* LBl = lds + 5120;
    int tid = threadIdx.x;
    int l15 = tid & 15, lhi = tid >> 4;
    float4v acc[3];
    acc[0] = (float4v){0.f, 0.f, 0.f, 0.f};
    acc[1] = (float4v){0.f, 0.f, 0.f, 0.f};
    acc[2] = (float4v){0.f, 0.f, 0.f, 0.f};

    for (int k0 = 0; k0 < 512; k0 += 64) {
#pragma unroll
        for (int it = 0; it < 2; ++it) {
            int i2 = it * 64 + tid;
            int row = i2 >> 3, ch = i2 & 7;
            int g = (t1b + row) * 1536 + k0 + ((ch ^ (row & 7)) << 3);
            gload16(&Ahg[g], LAh + ((it * 64) << 3));
            gload16(&Alg[g], LAl + ((it * 64) << 3));
        }
#pragma unroll
        for (int it = 0; it < 6; ++it) {
            int i2 = it * 64 + tid;
            int row = i2 >> 3, ch = i2 & 7;
            int t2 = t2b0 + row;
            int t2c = t2 < 0 ? 0 : (t2 > 127 ? 127 : t2);
            int g = t2c * 1536 + k0 + ((ch ^ (row & 7)) << 3);
            gload16(&Bhg[g], LBh + ((it * 64) << 3));
            gload16(&Blg[g], LBl + ((it * 64) << 3));
        }
        __syncthreads();
#pragma unroll
        for (int ks = 0; ks < 2; ++ks) {
            int offa = l15 * 64 + (((ks * 4 + lhi) ^ (l15 & 7)) * 8);
            short8 ah = *(const short8*)&LAh[offa];
            short8 al = *(const short8*)&LAl[offa];
#pragma unroll
            for (int tl = 0; tl < 3; ++tl) {
                int rb = tl * 16 + l15;
                int offb = rb * 64 + (((ks * 4 + lhi) ^ (rb & 7)) * 8);
                short8 bh = *(const short8*)&LBh[offb];
                short8 bl = *(const short8*)&LBl[offb];
                acc[tl] = __builtin_amdgcn_mfma_f32_16x16x32_bf16(ah, bh, acc[tl], 0, 0, 0);
                acc[tl] = __builtin_amdgcn_mfma_f32_16x16x32_bf16(ah, bl, acc[tl], 0, 0, 0);
                acc[tl] = __builtin_amdgcn_mfma_f32_16x16x32_bf16(al, bh, acc[tl], 0, 0, 0);
            }
        }
        __syncthreads();
    }
    float* Dm = D + mat * 16384;
#pragma unroll
    for (int tl = 0; tl < 3; ++tl) {
        int t2base = t2b0 + tl * 16;
        if (t2base < 0 || t2base > 127) continue;
        int t2 = t2base + l15;
#pragma unroll
        for (int i = 0; i < 4; ++i) {
            int t1 = t1b + lhi * 4 + i;
            Dm[t1 * 128 + t2] = acc[tl][i];
        }
    }
}

// ---------------------------------------------------------------------------
// MLP layer via MFMA: C[r][o] = lrelu( A[r,:] . W[o,:] )
// ---------------------------------------------------------------------------
template <bool SPLIT_OUT>
__global__ __launch_bounds__(256) void k_mlp(
    const unsigned short* __restrict__ Ahi, const unsigned short* __restrict__ Alo,
    const unsigned short* __restrict__ Bhi, const unsigned short* __restrict__ Blo,
    unsigned short* __restrict__ Ch, unsigned short* __restrict__ Cl,
    float* __restrict__ Cf) {
    __shared__ unsigned short lds[32768];
    int r0 = blockIdx.x * 128, o0 = blockIdx.y * 128;
    float4v acc[4][4];
#pragma unroll
    for (int m = 0; m < 4; ++m)
#pragma unroll
        for (int n = 0; n < 4; ++n) acc[m][n] = (float4v){0.f, 0.f, 0.f, 0.f};

    mfma_core(Ahi + r0 * 512, Alo + r0 * 512, 512, Bhi + o0 * 512, Blo + o0 * 512, 512, lds, acc);

    int lane = threadIdx.x & 63, wave = threadIdx.x >> 6;
    int wm = wave >> 1, wn = wave & 1, l15 = lane & 15, lhi = lane >> 4;
#pragma unroll
    for (int m = 0; m < 4; ++m)
#pragma unroll
        for (int n = 0; n < 4; ++n) {
            int o = o0 + wn * 64 + n * 16 + l15;
#pragma unroll
            for (int i = 0; i < 4; ++i) {
                int r = r0 + wm * 64 + m * 16 + lhi * 4 + i;
                float v = lrelu(acc[m][n][i]);
                if (SPLIT_OUT) {
                    unsigned short h = f2bf(v), l = f2bf(v - bf2f(h));
                    Ch[r * 512 + o] = h;
                    Cl[r * 512 + o] = l;
                } else {
                    Cf[r * 512 + o] = v;
                }
            }
        }
}

// ---------------------------------------------------------------------------
// Mix, 4 t's per block (r12 body; r13: float4 Pm reads -> 4 FMA per LDS
// issue, same accumulation order = bit-identical). grid 512 XCD-swizzled,
// block 512, one o per thread.
// ---------------------------------------------------------------------------
__global__ __launch_bounds__(512) void k_mix(
    const unsigned short* __restrict__ Xh, const unsigned short* __restrict__ Xl,
    const float* __restrict__ Wg, const float* __restrict__ D,
    const float* __restrict__ W_b, unsigned short* __restrict__ Plh,
    unsigned short* __restrict__ Pll) {
    int orig = blockIdx.x;
    int bid = ((orig & 7) << 6) | (orig >> 3);  // 512 = 8 * 64, bijective
    int b = bid >> 5, tg = bid & 31;
    int t0 = tg * 4;
    int tid = threadIdx.x;

    __shared__ float Pm[4][24][28];

    // gather f for 4 t's
    for (int idx = tid; idx < 4 * 576; idx += 512) {
        int dt = idx / 576, r = idx - dt * 576;
        int n = r / 24, m = r - n * 24;
        int t = t0 + dt;
        int j = n / 3, k = n - j * 3;
        int jp = m / 3, kp = m - jp * 3;
        int t1 = t - 7 + j, t2 = t - 7 + jp;
        float v = 0.f;
        if (t1 >= 0 && t2 >= 0)
            v = D[((((b * 3 + k) * 3 + kp) * 128 + t1) << 7) + t2];
        Pm[dt][n][m] = v;
    }
    __syncthreads();

    // softmax: 96 rows in parallel
    if (tid < 96) {
        int dt = tid / 24, n = tid - dt * 24;
        float mx = -1e30f;
#pragma unroll
        for (int m = 0; m < 24; ++m) mx = fmaxf(mx, Pm[dt][n][m]);
        float e[24], sum = 0.f;
#pragma unroll
        for (int m = 0; m < 24; ++m) { e[m] = __expf(Pm[dt][n][m] - mx); sum += e[m]; }
        float inv = 1.0f / sum;
#pragma unroll
        for (int m = 0; m < 24; ++m) Pm[dt][n][m] = e[m] * inv;
    }
    __syncthreads();

    int o = tid;
    // union preload: slot s <-> tp = t0 - 7 + s, s in [0, 10], x3 k
    float wg[33], xw[33];
#pragma unroll
    for (int s = 0; s < 11; ++s) {
        int tp = t0 - 7 + s;
#pragma unroll
        for (int k = 0; k < 3; ++k) {
            int base = (((b * 128 + tp) * 3 + k) << 9) + o;
            bool ok = (tp >= 0);
            wg[s * 3 + k] = ok ? Wg[base] : 0.f;
            xw[s * 3 + k] = ok ? (bf2f(Xh[base]) + bf2f(Xl[base])) : 0.f;
        }
    }
    float wb = W_b[o];
#pragma unroll
    for (int dt = 0; dt < 4; ++dt) {
        float pooled = -1e30f;
#pragma unroll
        for (int n = 0; n < 24; ++n) {
            float s0 = 0.f, s1 = 0.f, s2 = 0.f, s3 = 0.f;
#pragma unroll
            for (int mq = 0; mq < 6; ++mq) {
                float4 p4 = *(const float4*)&Pm[dt][n][mq * 4];  // ds_read_b128, broadcast
                s0 += p4.x * wg[mq * 4 + 0 + dt * 3];
                s1 += p4.y * wg[mq * 4 + 1 + dt * 3];
                s2 += p4.z * wg[mq * 4 + 2 + dt * 3];
                s3 += p4.w * wg[mq * 4 + 3 + dt * 3];
            }
            float s = ((s0 + s1) + (s2 + s3)) + wb + xw[n + dt * 3];
            pooled = fmaxf(pooled, s);
        }
        int t = t0 + dt;
        int oidx = ((t * 16 + b) << 9) + o;
        unsigned short h = f2bf(pooled), l = f2bf(pooled - bf2f(h));
        Plh[oidx] = h;
        Pll[oidx] = l;
    }
}

// ---------------------------------------------------------------------------
// out[r] = lrelu( sum_c H[r][c]*p3w[c] + p3b )   one wave per row
// ---------------------------------------------------------------------------
__global__ __launch_bounds__(256) void k_final(const float* __restrict__ H,
                                               const float* __restrict__ p3w,
                                               const float* __restrict__ p3b,
                                               float* __restrict__ out) {
    int r = blockIdx.x * 4 + (threadIdx.x >> 6);
    int lane = threadIdx.x & 63;
    const float4* h4 = (const float4*)&H[r << 9];
    const float4* w4 = (const float4*)p3w;
    float4 a1 = h4[lane], a2 = h4[lane + 64];
    float4 b1 = w4[lane], b2 = w4[lane + 64];
    float s = a1.x * b1.x + a1.y * b1.y + a1.z * b1.z + a1.w * b1.w +
              a2.x * b2.x + a2.y * b2.y + a2.z * b2.z + a2.w * b2.w;
#pragma unroll
    for (int off = 32; off; off >>= 1) s += __shfl_down(s, off, 64);
    if (lane == 0) out[r] = lrelu(s + p3b[0]);
}

extern "C" void kernel_launch(void* const* d_in, const int* in_sizes, int n_in,
                              void* d_out, int out_size, void* d_ws, size_t ws_size,
                              hipStream_t stream) {
    const float* out1 = (const float*)d_in[0];
    const float* out2 = (const float*)d_in[1];
    const float* out3 = (const float*)d_in[2];
    const float* theta_w = (const float*)d_in[3];
    const float* phi_w = (const float*)d_in[4];
    const float* g_w = (const float*)d_in[5];
    const float* W_w = (const float*)d_in[6];
    const float* W_b = (const float*)d_in[7];
    const float* p1_w = (const float*)d_in[8];
    const float* p2_w = (const float*)d_in[9];
    const float* p3_w = (const float*)d_in[10];
    const float* p3_b = (const float*)d_in[11];
    float* outp = (float*)d_out;

    // ---- workspace layout (bytes) ----
    char* wsb = (char*)d_ws;
    unsigned short* Whi = (unsigned short*)(wsb + 0);         // 1024x512 bf16 (Mw | Wg_w)
    unsigned short* Wlo = (unsigned short*)(wsb + 1048576);
    unsigned short* p1h = (unsigned short*)(wsb + 2097152);
    unsigned short* p1l = (unsigned short*)(wsb + 2621440);
    unsigned short* p2h = (unsigned short*)(wsb + 3145728);
    unsigned short* p2l = (unsigned short*)(wsb + 3670016);
    unsigned short* WwH = (unsigned short*)(wsb + 4194304);
    unsigned short* WwL = (unsigned short*)(wsb + 4718592);
    unsigned short* TtH = (unsigned short*)(wsb + 5242880);
    unsigned short* TtL = (unsigned short*)(wsb + 5767168);
    unsigned short* PtH = (unsigned short*)(wsb + 6291456);
    unsigned short* PtL = (unsigned short*)(wsb + 6815744);
    unsigned short* GtH = (unsigned short*)(wsb + 7340032);
    unsigned short* GtL = (unsigned short*)(wsb + 7864320);
    unsigned short* Xh  = (unsigned short*)(wsb + 8388608);   // 6144x512 bf16
    unsigned short* Xl  = (unsigned short*)(wsb + 14680064);
    unsigned short* Yh  = (unsigned short*)(wsb + 20971520);  // 6144x512 bf16
    unsigned short* Yl  = (unsigned short*)(wsb + 27262976);
    float* Wg = (float*)(wsb + 33554432);                     // 6144x512 fp32
    float* D  = (float*)(wsb + 46137344);                     // 144x128x128 fp32
    // aliases (dead-buffer reuse):
    unsigned short* Plh = (unsigned short*)(wsb + 20971520);  // over Yh (dead after gram)
    unsigned short* Pll = (unsigned short*)(wsb + 23068672);
    unsigned short* h1h = (unsigned short*)(wsb + 27262976);  // over Yl (dead after gram)
    unsigned short* h1l = (unsigned short*)(wsb + 29360128);
    float* h2 = (float*)(wsb + 8388608);                      // over Xh (dead after mix)

    // 1. split raw weights: straight (W_w, p1, p2) + transposed (theta, phi, g)
    k_split_w<<<dim3(256, 3), 256, 0, stream>>>(W_w, p1_w, p2_w,
                                                WwH, WwL, p1h, p1l, p2h, p2l);
    k_split_wT<<<dim3(16, 16, 3), dim3(32, 8), 0, stream>>>(theta_w, phi_w, g_w,
                                                            TtH, TtL, PtH, PtL, GtH, GtL);
    // 2. transpose+split inputs (independent of weight GEMMs)
    k_splitx<<<dim3(16, 4, 48), dim3(32, 8), 0, stream>>>(out1, out2, out3, Xh, Xl);
    // 3. weight GEMMs via MFMA: Mw = Tt.Pt^T ; Wg_w = Ww.Gt^T -> Whi/Wlo stacked
    k_wgemm<<<dim3(4, 4, 2), 256, 0, stream>>>(WwH, WwL, GtH, GtL, TtH, TtL,
                                               PtH, PtL, Whi, Wlo);
    // 4. stage A: Y (bf16 hi/lo) + Wg (fp32)
    k_ga<<<dim3(48, 8), 256, 0, stream>>>(Whi, Wlo, Xh, Xl, Yh, Yl, Wg);
    // 5. band gram matrices: D = X . Y^T, |t1-t2| <= 7 only
    k_gram3<<<dim3(1152), 64, 0, stream>>>(Xh, Xl, Yh, Yl, D);
    // 6. softmax + mix + residual + pool (4 t's per block)
    k_mix<<<dim3(512), 512, 0, stream>>>(Xh, Xl, Wg, D, W_b, Plh, Pll);
    // 7. MLP
    k_mlp<true><<<dim3(16, 4), 256, 0, stream>>>(Plh, Pll, p1h, p1l, h1h, h1l, nullptr);
    k_mlp<false><<<dim3(16, 4), 256, 0, stream>>>(h1h, h1l, p2h, p2l, nullptr, nullptr, h2);
    // 8. final projection
    k_final<<<dim3(512), 256, 0, stream>>>(h2, p3_w, p3_b, outp);
}

// Round 14
// 134.145 us; speedup vs baseline: 1.4665x; 1.0374x over previous
//
#include <hip/hip_runtime.h>

typedef __attribute__((ext_vector_type(8))) short short8;
typedef __attribute__((ext_vector_type(4))) float float4v;
typedef __attribute__((ext_vector_type(4))) unsigned int uint4v;
typedef __attribute__((ext_vector_type(4))) unsigned short ushort4v;

__device__ __forceinline__ float lrelu(float v) { return v >= 0.f ? v : 0.01f * v; }

__device__ __forceinline__ unsigned short f2bf(float x) {
    union { float f; unsigned u; } c; c.f = x;
    unsigned r = (c.u + 0x7FFFu + ((c.u >> 16) & 1u)) >> 16;
    return (unsigned short)r;
}
__device__ __forceinline__ float bf2f(unsigned short h) {
    union { unsigned u; float f; } c; c.u = ((unsigned)h) << 16;
    return c.f;
}

// async global->LDS, 16B per lane. LDS dest must be wave-uniform base
// (HW adds lane*16); global src is per-lane (pre-swizzled).
__device__ __forceinline__ void gload16(const unsigned short* g, unsigned short* l) {
    __builtin_amdgcn_global_load_lds(
        (const __attribute__((address_space(1))) unsigned int*)g,
        (__attribute__((address_space(3))) unsigned int*)l, 16, 0, 0);
}

// ===========================================================================
// Shared MFMA core: C[128x128] += A[128xK] * B[128xK]^T, K=512, split-bf16
// (hi*hi + hi*lo + lo*hi -> ~fp32 precision). 256 threads, 4 waves 2x2.
// LDS: 4 tiles [128][64] bf16. global_load_lds direct staging: LDS linear,
// global source pre-swizzled with the same XOR involution the reads use.
// ===========================================================================
__device__ __forceinline__ void mfma_core(
    const unsigned short* __restrict__ Ah, const unsigned short* __restrict__ Al, int lda,
    const unsigned short* __restrict__ Bh, const unsigned short* __restrict__ Bl, int ldb,
    unsigned short* lds, float4v acc[4][4]) {
    const int tid = threadIdx.x;
    const int lane = tid & 63, wave = tid >> 6;
    const int wm = wave >> 1, wn = wave & 1;
    const int l15 = lane & 15, lhi = lane >> 4;
    unsigned short* LAh = lds;
    unsigned short* LAl = lds + 8192;
    unsigned short* LBh = lds + 16384;
    unsigned short* LBl = lds + 24576;

    for (int k0 = 0; k0 < 512; k0 += 64) {
#pragma unroll
        for (int tile = 0; tile < 4; ++tile) {
            const unsigned short* s = (tile == 0) ? Ah : (tile == 1) ? Al : (tile == 2) ? Bh : Bl;
            int ld = (tile < 2) ? lda : ldb;
            unsigned short* dbase = lds + tile * 8192;
#pragma unroll
            for (int it = 0; it < 4; ++it) {
                int idx = it * 256 + tid;
                int row = idx >> 3, ch = idx & 7;
                // linear LDS dest (wave-uniform base), swizzled global src
                gload16(&s[row * ld + k0 + ((ch ^ (row & 7)) << 3)],
                        dbase + ((it * 256 + wave * 64) << 3));
            }
        }
        __syncthreads();
#pragma unroll
        for (int ks = 0; ks < 2; ++ks) {
            short8 ah[4], al[4], bh[4], bl[4];
#pragma unroll
            for (int m = 0; m < 4; ++m) {
                int r = wm * 64 + m * 16 + l15;
                int off = r * 64 + (((ks * 4 + lhi) ^ (r & 7)) * 8);
                ah[m] = *(const short8*)&LAh[off];
                al[m] = *(const short8*)&LAl[off];
            }
#pragma unroll
            for (int n = 0; n < 4; ++n) {
                int r = wn * 64 + n * 16 + l15;
                int off = r * 64 + (((ks * 4 + lhi) ^ (r & 7)) * 8);
                bh[n] = *(const short8*)&LBh[off];
                bl[n] = *(const short8*)&LBl[off];
            }
#pragma unroll
            for (int m = 0; m < 4; ++m)
#pragma unroll
                for (int n = 0; n < 4; ++n) {
                    acc[m][n] = __builtin_amdgcn_mfma_f32_16x16x32_bf16(ah[m], bh[n], acc[m][n], 0, 0, 0);
                    acc[m][n] = __builtin_amdgcn_mfma_f32_16x16x32_bf16(ah[m], bl[n], acc[m][n], 0, 0, 0);
                    acc[m][n] = __builtin_amdgcn_mfma_f32_16x16x32_bf16(al[m], bh[n], acc[m][n], 0, 0, 0);
                }
        }
        __syncthreads();
    }
}

// ---------------------------------------------------------------------------
// Fused weight splits (r14): grid (16,16,6), block (32,8).
// z 0-2: transpose-split theta/phi/g_w -> Tt/Pt/Gt (Dst[i][k] = src[k][i])
// z 3-5: straight-split W_w/p1_w/p2_w -> WwH/L, p1h/l, p2h/l
// ---------------------------------------------------------------------------
__global__ __launch_bounds__(256) void k_splitw6(
    const float* __restrict__ tw, const float* __restrict__ fw,
    const float* __restrict__ gw, const float* __restrict__ ww,
    const float* __restrict__ p1w, const float* __restrict__ p2w,
    unsigned short* __restrict__ TtH, unsigned short* __restrict__ TtL,
    unsigned short* __restrict__ PtH, unsigned short* __restrict__ PtL,
    unsigned short* __restrict__ GtH, unsigned short* __restrict__ GtL,
    unsigned short* __restrict__ WwH, unsigned short* __restrict__ WwL,
    unsigned short* __restrict__ p1h, unsigned short* __restrict__ p1l,
    unsigned short* __restrict__ p2h, unsigned short* __restrict__ p2l) {
    int z = blockIdx.z;
    int i0 = blockIdx.x * 32, k0 = blockIdx.y * 32;
    int tx = threadIdx.x, ty = threadIdx.y;
    __shared__ float tile[32][33];
    if (z < 3) {
        const float* src = (z == 0) ? tw : (z == 1) ? fw : gw;
        unsigned short* dh = (z == 0) ? TtH : (z == 1) ? PtH : GtH;
        unsigned short* dl = (z == 0) ? TtL : (z == 1) ? PtL : GtL;
#pragma unroll
        for (int i = 0; i < 4; ++i)
            tile[ty + i * 8][tx] = src[(k0 + ty + i * 8) * 512 + i0 + tx];
        __syncthreads();
#pragma unroll
        for (int i = 0; i < 4; ++i) {
            int row = i0 + ty + i * 8;
            float v = tile[tx][ty + i * 8];  // = src[k0+tx][row]
            unsigned short h = f2bf(v), l = f2bf(v - bf2f(h));
            int idx = row * 512 + k0 + tx;
            dh[idx] = h;
            dl[idx] = l;
        }
    } else {
        const float* src = (z == 3) ? ww : (z == 4) ? p1w : p2w;
        unsigned short* dh = (z == 3) ? WwH : (z == 4) ? p1h : p2h;
        unsigned short* dl = (z == 3) ? WwL : (z == 4) ? p1l : p2l;
#pragma unroll
        for (int i = 0; i < 4; ++i) {
            int r = k0 + ty + i * 8;
            int idx = r * 512 + i0 + tx;
            float v = src[idx];
            unsigned short h = f2bf(v), l = f2bf(v - bf2f(h));
            dh[idx] = h;
            dl[idx] = l;
        }
    }
}

// ---------------------------------------------------------------------------
// Weight GEMMs via MFMA, epilogue splits into stacked Whi/Wlo [1024][512]:
//   z=1: Mw   = Tt . Pt^T -> rows 0-511    (Mw[i][j] = sum_k theta[k][i] phi[k][j])
//   z=0: Wg_w = Ww . Gt^T -> rows 512-1023 (Wg_w[i][j] = sum_k W_w[i][k] g_w[k][j])
// grid (4,4,2), block 256.
// ---------------------------------------------------------------------------
__global__ __launch_bounds__(256) void k_wgemm(
    const unsigned short* __restrict__ WwH, const unsigned short* __restrict__ WwL,
    const unsigned short* __restrict__ GtH, const unsigned short* __restrict__ GtL,
    const unsigned short* __restrict__ TtH, const unsigned short* __restrict__ TtL,
    const unsigned short* __restrict__ PtH, const unsigned short* __restrict__ PtL,
    unsigned short* __restrict__ Whi, unsigned short* __restrict__ Wlo) {
    __shared__ unsigned short lds[32768];
    int i0 = blockIdx.y * 128, j0 = blockIdx.x * 128;
    bool wg = blockIdx.z == 0;
    const unsigned short* Ah = (wg ? WwH : TtH) + i0 * 512;
    const unsigned short* Al = (wg ? WwL : TtL) + i0 * 512;
    const unsigned short* Bh = (wg ? GtH : PtH) + j0 * 512;
    const unsigned short* Bl = (wg ? GtL : PtL) + j0 * 512;
    float4v acc[4][4];
#pragma unroll
    for (int m = 0; m < 4; ++m)
#pragma unroll
        for (int n = 0; n < 4; ++n) acc[m][n] = (float4v){0.f, 0.f, 0.f, 0.f};

    mfma_core(Ah, Al, 512, Bh, Bl, 512, lds, acc);

    int lane = threadIdx.x & 63, wave = threadIdx.x >> 6;
    int wm = wave >> 1, wn = wave & 1, l15 = lane & 15, lhi = lane >> 4;
    int rowbase = wg ? 512 + i0 : i0;
#pragma unroll
    for (int m = 0; m < 4; ++m)
#pragma unroll
        for (int n = 0; n < 4; ++n) {
            int bcol = j0 + wn * 64 + n * 16 + l15;
#pragma unroll
            for (int i = 0; i < 4; ++i) {
                int r = rowbase + wm * 64 + m * 16 + lhi * 4 + i;
                float v = acc[m][n][i];
                unsigned short h = f2bf(v), l = f2bf(v - bf2f(h));
                Whi[r * 512 + bcol] = h;
                Wlo[r * 512 + bcol] = l;
            }
        }
}

// ---------------------------------------------------------------------------
// Transpose+split inputs: Xt[((b*128+t)*3+k)*512 + c] = in_k[b][c][t]
// (bf16 hi/lo + fp32 copy Xf for k_mix's residual path — r14).
// ---------------------------------------------------------------------------
__global__ __launch_bounds__(256) void k_splitx(const float* __restrict__ o1,
                                                const float* __restrict__ o2,
                                                const float* __restrict__ o3,
                                                unsigned short* __restrict__ Xh,
                                                unsigned short* __restrict__ Xl,
                                                float* __restrict__ Xf) {
    int z = blockIdx.z;
    int b = z / 3, k = z - b * 3;
    const float* In = (k == 0) ? o1 : ((k == 1) ? o2 : o3);
    int c0 = blockIdx.x * 32, t0 = blockIdx.y * 32;
    __shared__ float tile[32][33];
    int tx = threadIdx.x, ty = threadIdx.y;
#pragma unroll
    for (int i = 0; i < 4; ++i)
        tile[ty + i * 8][tx] = In[(b * 512 + c0 + ty + i * 8) * 128 + t0 + tx];
    __syncthreads();
#pragma unroll
    for (int i = 0; i < 4; ++i) {
        int t = t0 + ty + i * 8;
        float v = tile[tx][ty + i * 8];
        unsigned short h = f2bf(v), l = f2bf(v - bf2f(h));
        int idx = ((b * 128 + t) * 3 + k) * 512 + c0 + tx;
        Xh[idx] = h;
        Xl[idx] = l;
        Xf[idx] = v;
    }
}

// ---------------------------------------------------------------------------
// Stage A via MFMA: grid (48, 8): x = b*3+kin, y = o-tile
//   y 0-3 -> Y = Mw . x (bf16 hi/lo), y 4-7 -> Wg = Wg_w . x (fp32)
// ---------------------------------------------------------------------------
__global__ __launch_bounds__(256) void k_ga(
    const unsigned short* __restrict__ Whi, const unsigned short* __restrict__ Wlo,
    const unsigned short* __restrict__ Xh, const unsigned short* __restrict__ Xl,
    unsigned short* __restrict__ Yh, unsigned short* __restrict__ Yl,
    float* __restrict__ Wg) {
    __shared__ unsigned short lds[32768];
    int bk = blockIdx.x, y = blockIdx.y;
    int b = bk / 3, kin = bk - b * 3;
    int bbase = (b * 384 + kin) * 512;
    float4v acc[4][4];
#pragma unroll
    for (int m = 0; m < 4; ++m)
#pragma unroll
        for (int n = 0; n < 4; ++n) acc[m][n] = (float4v){0.f, 0.f, 0.f, 0.f};

    mfma_core(Whi + y * 128 * 512, Wlo + y * 128 * 512, 512,
              Xh + bbase, Xl + bbase, 1536, lds, acc);

    int lane = threadIdx.x & 63, wave = threadIdx.x >> 6;
    int wm = wave >> 1, wn = wave & 1, l15 = lane & 15, lhi = lane >> 4;
    int wsel = y >> 2, o0 = (y & 3) * 128;
#pragma unroll
    for (int m = 0; m < 4; ++m)
#pragma unroll
        for (int n = 0; n < 4; ++n) {
            int o_in = wm * 64 + m * 16 + lhi * 4;
            int t = wn * 64 + n * 16 + l15;
            int idx = bbase + t * 1536 + o0 + o_in;
            if (wsel == 1) {
                *(float4v*)&Wg[idx] = acc[m][n];
            } else {
                ushort4v h, l;
#pragma unroll
                for (int i = 0; i < 4; ++i) {
                    float v = acc[m][n][i];
                    h[i] = f2bf(v);
                    l[i] = f2bf(v - bf2f(h[i]));
                }
                *(ushort4v*)&Yh[idx] = h;
                *(ushort4v*)&Yl[idx] = l;
            }
        }
}

// ---------------------------------------------------------------------------
// Band gram: k_mix only reads |t1-t2|<=7, so compute only the band.
// grid 1152 = (mat, t1-chunk c) XCD-swizzled, block 64 (1 wave).
// ---------------------------------------------------------------------------
__global__ __launch_bounds__(64) void k_gram3(
    const unsigned short* __restrict__ Xh, const unsigned short* __restrict__ Xl,
    const unsigned short* __restrict__ Yh, const unsigned short* __restrict__ Yl,
    float* __restrict__ D) {
    __shared__ unsigned short lds[8192];  // Ah[16][64] Al[16][64] Bh[48][64] Bl[48][64]
    int orig = blockIdx.x;
    int idx = (orig & 7) * 144 + (orig >> 3);  // 1152 = 8*144, bijective
    int mat = idx >> 3, c = idx & 7;
    int b = mat / 9, r9 = mat - b * 9, k = r9 / 3, kp = r9 - k * 3;
    const unsigned short* Ahg = Xh + (b * 384 + k) * 512;
    const unsigned short* Alg = Xl + (b * 384 + k) * 512;
    const unsigned short* Bhg = Yh + (b * 384 + kp) * 512;
    const unsigned short* Blg = Yl + (b * 384 + kp) * 512;
    int t1b = c * 16, t2b0 = c * 16 - 16;
    unsigned short* LAh = lds;          // [16][64]
    unsigned short* LAl = lds + 1024;
    unsigned short* LBh = lds + 2048;   // [48][64]
    unsigned short* LBl = lds + 5120;
    int tid = threadIdx.x;
    int l15 = tid & 15, lhi = tid >> 4;
    float4v acc[3];
    acc[0] = (float4v){0.f, 0.f, 0.f, 0.f};
    acc[1] = (float4v){0.f, 0.f, 0.f, 0.f};
    acc[2] = (float4v){0.f, 0.f, 0.f, 0.f};

    for (int k0 = 0; k0 < 512; k0 += 64) {
#pragma unroll
        for (int it = 0; it < 2; ++it) {
            int i2 = it * 64 + tid;
            int row = i2 >> 3, ch = i2 & 7;
            int g = (t1b + row) * 1536 + k0 + ((ch ^ (row & 7)) << 3);
            gload16(&Ahg[g], LAh + ((it * 64) << 3));
            gload16(&Alg[g], LAl + ((it * 64) << 3));
        }
#pragma unroll
        for (int it = 0; it < 6; ++it) {
            int i2 = it * 64 + tid;
            int row = i2 >> 3, ch = i2 & 7;
            int t2 = t2b0 + row;
            int t2c = t2 < 0 ? 0 : (t2 > 127 ? 127 : t2);
            int g = t2c * 1536 + k0 + ((ch ^ (row & 7)) << 3);
            gload16(&Bhg[g], LBh + ((it * 64) << 3));
            gload16(&Blg[g], LBl + ((it * 64) << 3));
        }
        __syncthreads();
#pragma unroll
        for (int ks = 0; ks < 2; ++ks) {
            int offa = l15 * 64 + (((ks * 4 + lhi) ^ (l15 & 7)) * 8);
            short8 ah = *(const short8*)&LAh[offa];
            short8 al = *(const short8*)&LAl[offa];
#pragma unroll
            for (int tl = 0; tl < 3; ++tl) {
                int rb = tl * 16 + l15;
                int offb = rb * 64 + (((ks * 4 + lhi) ^ (rb & 7)) * 8);
                short8 bh = *(const short8*)&LBh[offb];
                short8 bl = *(const short8*)&LBl[offb];
                acc[tl] = __builtin_amdgcn_mfma_f32_16x16x32_bf16(ah, bh, acc[tl], 0, 0, 0);
                acc[tl] = __builtin_amdgcn_mfma_f32_16x16x32_bf16(ah, bl, acc[tl], 0, 0, 0);
                acc[tl] = __builtin_amdgcn_mfma_f32_16x16x32_bf16(al, bh, acc[tl], 0, 0, 0);
            }
        }
        __syncthreads();
    }
    float* Dm = D + mat * 16384;
#pragma unroll
    for (int tl = 0; tl < 3; ++tl) {
        int t2base = t2b0 + tl * 16;
        if (t2base < 0 || t2base > 127) continue;
        int t2 = t2base + l15;
#pragma unroll
        for (int i = 0; i < 4; ++i) {
            int t1 = t1b + lhi * 4 + i;
            Dm[t1 * 128 + t2] = acc[tl][i];
        }
    }
}

// ---------------------------------------------------------------------------
// MLP layer via MFMA: C[r][o] = lrelu( A[r,:] . W[o,:] )
// ---------------------------------------------------------------------------
template <bool SPLIT_OUT>
__global__ __launch_bounds__(256) void k_mlp(
    const unsigned short* __restrict__ Ahi, const unsigned short* __restrict__ Alo,
    const unsigned short* __restrict__ Bhi, const unsigned short* __restrict__ Blo,
    unsigned short* __restrict__ Ch, unsigned short* __restrict__ Cl,
    float* __restrict__ Cf) {
    __shared__ unsigned short lds[32768];
    int r0 = blockIdx.x * 128, o0 = blockIdx.y * 128;
    float4v acc[4][4];
#pragma unroll
    for (int m = 0; m < 4; ++m)
#pragma unroll
        for (int n = 0; n < 4; ++n) acc[m][n] = (float4v){0.f, 0.f, 0.f, 0.f};

    mfma_core(Ahi + r0 * 512, Alo + r0 * 512, 512, Bhi + o0 * 512, Blo + o0 * 512, 512, lds, acc);

    int lane = threadIdx.x & 63, wave = threadIdx.x >> 6;
    int wm = wave >> 1, wn = wave & 1, l15 = lane & 15, lhi = lane >> 4;
#pragma unroll
    for (int m = 0; m < 4; ++m)
#pragma unroll
        for (int n = 0; n < 4; ++n) {
            int o = o0 + wn * 64 + n * 16 + l15;
#pragma unroll
            for (int i = 0; i < 4; ++i) {
                int r = r0 + wm * 64 + m * 16 + lhi * 4 + i;
                float v = lrelu(acc[m][n][i]);
                if (SPLIT_OUT) {
                    unsigned short h = f2bf(v), l = f2bf(v - bf2f(h));
                    Ch[r * 512 + o] = h;
                    Cl[r * 512 + o] = l;
                } else {
                    Cf[r * 512 + o] = v;
                }
            }
        }
}

// ---------------------------------------------------------------------------
// Mix, 4 t's per block (r13 body; r14: fp32 Xf residual loads — 1 load
// instead of 2 bf16 + decode). grid 512 XCD-swizzled, block 512.
// ---------------------------------------------------------------------------
__global__ __launch_bounds__(512) void k_mix(
    const float* __restrict__ Xf, const float* __restrict__ Wg,
    const float* __restrict__ D, const float* __restrict__ W_b,
    unsigned short* __restrict__ Plh, unsigned short* __restrict__ Pll) {
    int orig = blockIdx.x;
    int bid = ((orig & 7) << 6) | (orig >> 3);  // 512 = 8 * 64, bijective
    int b = bid >> 5, tg = bid & 31;
    int t0 = tg * 4;
    int tid = threadIdx.x;

    __shared__ float Pm[4][24][28];

    // gather f for 4 t's
    for (int idx = tid; idx < 4 * 576; idx += 512) {
        int dt = idx / 576, r = idx - dt * 576;
        int n = r / 24, m = r - n * 24;
        int t = t0 + dt;
        int j = n / 3, k = n - j * 3;
        int jp = m / 3, kp = m - jp * 3;
        int t1 = t - 7 + j, t2 = t - 7 + jp;
        float v = 0.f;
        if (t1 >= 0 && t2 >= 0)
            v = D[((((b * 3 + k) * 3 + kp) * 128 + t1) << 7) + t2];
        Pm[dt][n][m] = v;
    }
    __syncthreads();

    // softmax: 96 rows in parallel
    if (tid < 96) {
        int dt = tid / 24, n = tid - dt * 24;
        float mx = -1e30f;
#pragma unroll
        for (int m = 0; m < 24; ++m) mx = fmaxf(mx, Pm[dt][n][m]);
        float e[24], sum = 0.f;
#pragma unroll
        for (int m = 0; m < 24; ++m) { e[m] = __expf(Pm[dt][n][m] - mx); sum += e[m]; }
        float inv = 1.0f / sum;
#pragma unroll
        for (int m = 0; m < 24; ++m) Pm[dt][n][m] = e[m] * inv;
    }
    __syncthreads();

    int o = tid;
    // union preload: slot s <-> tp = t0 - 7 + s, s in [0, 10], x3 k
    float wg[33], xw[33];
#pragma unroll
    for (int s = 0; s < 11; ++s) {
        int tp = t0 - 7 + s;
#pragma unroll
        for (int k = 0; k < 3; ++k) {
            int base = (((b * 128 + tp) * 3 + k) << 9) + o;
            bool ok = (tp >= 0);
            wg[s * 3 + k] = ok ? Wg[base] : 0.f;
            xw[s * 3 + k] = ok ? Xf[base] : 0.f;
        }
    }
    float wb = W_b[o];
#pragma unroll
    for (int dt = 0; dt < 4; ++dt) {
        float pooled = -1e30f;
#pragma unroll
        for (int n = 0; n < 24; ++n) {
            float s0 = 0.f, s1 = 0.f, s2 = 0.f, s3 = 0.f;
#pragma unroll
            for (int mq = 0; mq < 6; ++mq) {
                float4 p4 = *(const float4*)&Pm[dt][n][mq * 4];  // ds_read_b128, broadcast
                s0 += p4.x * wg[mq * 4 + 0 + dt * 3];
                s1 += p4.y * wg[mq * 4 + 1 + dt * 3];
                s2 += p4.z * wg[mq * 4 + 2 + dt * 3];
                s3 += p4.w * wg[mq * 4 + 3 + dt * 3];
            }
            float s = ((s0 + s1) + (s2 + s3)) + wb + xw[n + dt * 3];
            pooled = fmaxf(pooled, s);
        }
        int t = t0 + dt;
        int oidx = ((t * 16 + b) << 9) + o;
        unsigned short h = f2bf(pooled), l = f2bf(pooled - bf2f(h));
        Plh[oidx] = h;
        Pll[oidx] = l;
    }
}

// ---------------------------------------------------------------------------
// out[r] = lrelu( sum_c H[r][c]*p3w[c] + p3b )   one wave per row
// ---------------------------------------------------------------------------
__global__ __launch_bounds__(256) void k_final(const float* __restrict__ H,
                                               const float* __restrict__ p3w,
                                               const float* __restrict__ p3b,
                                               float* __restrict__ out) {
    int r = blockIdx.x * 4 + (threadIdx.x >> 6);
    int lane = threadIdx.x & 63;
    const float4* h4 = (const float4*)&H[r << 9];
    const float4* w4 = (const float4*)p3w;
    float4 a1 = h4[lane], a2 = h4[lane + 64];
    float4 b1 = w4[lane], b2 = w4[lane + 64];
    float s = a1.x * b1.x + a1.y * b1.y + a1.z * b1.z + a1.w * b1.w +
              a2.x * b2.x + a2.y * b2.y + a2.z * b2.z + a2.w * b2.w;
#pragma unroll
    for (int off = 32; off; off >>= 1) s += __shfl_down(s, off, 64);
    if (lane == 0) out[r] = lrelu(s + p3b[0]);
}

extern "C" void kernel_launch(void* const* d_in, const int* in_sizes, int n_in,
                              void* d_out, int out_size, void* d_ws, size_t ws_size,
                              hipStream_t stream) {
    const float* out1 = (const float*)d_in[0];
    const float* out2 = (const float*)d_in[1];
    const float* out3 = (const float*)d_in[2];
    const float* theta_w = (const float*)d_in[3];
    const float* phi_w = (const float*)d_in[4];
    const float* g_w = (const float*)d_in[5];
    const float* W_w = (const float*)d_in[6];
    const float* W_b = (const float*)d_in[7];
    const float* p1_w = (const float*)d_in[8];
    const float* p2_w = (const float*)d_in[9];
    const float* p3_w = (const float*)d_in[10];
    const float* p3_b = (const float*)d_in[11];
    float* outp = (float*)d_out;

    // ---- workspace layout (bytes) ----
    char* wsb = (char*)d_ws;
    unsigned short* Whi = (unsigned short*)(wsb + 0);         // 1024x512 bf16 (Mw | Wg_w)
    unsigned short* Wlo = (unsigned short*)(wsb + 1048576);
    unsigned short* p1h = (unsigned short*)(wsb + 2097152);
    unsigned short* p1l = (unsigned short*)(wsb + 2621440);
    unsigned short* p2h = (unsigned short*)(wsb + 3145728);
    unsigned short* p2l = (unsigned short*)(wsb + 3670016);
    unsigned short* WwH = (unsigned short*)(wsb + 4194304);
    unsigned short* WwL = (unsigned short*)(wsb + 4718592);
    unsigned short* TtH = (unsigned short*)(wsb + 5242880);
    unsigned short* TtL = (unsigned short*)(wsb + 5767168);
    unsigned short* PtH = (unsigned short*)(wsb + 6291456);
    unsigned short* PtL = (unsigned short*)(wsb + 6815744);
    unsigned short* GtH = (unsigned short*)(wsb + 7340032);
    unsigned short* GtL = (unsigned short*)(wsb + 7864320);
    unsigned short* Xh  = (unsigned short*)(wsb + 8388608);   // 6144x512 bf16
    unsigned short* Xl  = (unsigned short*)(wsb + 14680064);
    unsigned short* Yh  = (unsigned short*)(wsb + 20971520);  // 6144x512 bf16
    unsigned short* Yl  = (unsigned short*)(wsb + 27262976);
    float* Wg = (float*)(wsb + 33554432);                     // 6144x512 fp32
    float* D  = (float*)(wsb + 46137344);                     // 144x128x128 fp32 -> ends 55574528
    float* Xf = (float*)(wsb + 55574528);                     // 6144x512 fp32 -> ends 68157440
    // aliases (dead-buffer reuse):
    unsigned short* Plh = (unsigned short*)(wsb + 20971520);  // over Yh (dead after gram)
    unsigned short* Pll = (unsigned short*)(wsb + 23068672);
    unsigned short* h1h = (unsigned short*)(wsb + 27262976);  // over Yl (dead after gram)
    unsigned short* h1l = (unsigned short*)(wsb + 29360128);
    float* h2 = (float*)(wsb + 8388608);                      // over Xh (dead after mix)

    // 1. fused weight splits: transpose (theta,phi,g) + straight (W_w,p1,p2)
    k_splitw6<<<dim3(16, 16, 6), dim3(32, 8), 0, stream>>>(
        theta_w, phi_w, g_w, W_w, p1_w, p2_w,
        TtH, TtL, PtH, PtL, GtH, GtL, WwH, WwL, p1h, p1l, p2h, p2l);
    // 2. transpose+split inputs (+ fp32 Xf copy)
    k_splitx<<<dim3(16, 4, 48), dim3(32, 8), 0, stream>>>(out1, out2, out3, Xh, Xl, Xf);
    // 3. weight GEMMs via MFMA: Mw = Tt.Pt^T ; Wg_w = Ww.Gt^T -> Whi/Wlo stacked
    k_wgemm<<<dim3(4, 4, 2), 256, 0, stream>>>(WwH, WwL, GtH, GtL, TtH, TtL,
                                               PtH, PtL, Whi, Wlo);
    // 4. stage A: Y (bf16 hi/lo) + Wg (fp32)
    k_ga<<<dim3(48, 8), 256, 0, stream>>>(Whi, Wlo, Xh, Xl, Yh, Yl, Wg);
    // 5. band gram matrices: D = X . Y^T, |t1-t2| <= 7 only
    k_gram3<<<dim3(1152), 64, 0, stream>>>(Xh, Xl, Yh, Yl, D);
    // 6. softmax + mix + residual + pool (4 t's per block)
    k_mix<<<dim3(512), 512, 0, stream>>>(Xf, Wg, D, W_b, Plh, Pll);
    // 7. MLP
    k_mlp<true><<<dim3(16, 4), 256, 0, stream>>>(Plh, Pll, p1h, p1l, h1h, h1l, nullptr);
    k_mlp<false><<<dim3(16, 4), 256, 0, stream>>>(h1h, h1l, p2h, p2l, nullptr, nullptr, h2);
    // 8. final projection
    k_final<<<dim3(512), 256, 0, stream>>>(h2, p3_w, p3_b, outp);
}

// Round 15
// 122.866 us; speedup vs baseline: 1.6011x; 1.0918x over previous
//
#include <hip/hip_runtime.h>

typedef __attribute__((ext_vector_type(8))) short short8;
typedef __attribute__((ext_vector_type(4))) float float4v;
typedef __attribute__((ext_vector_type(4))) unsigned int uint4v;
typedef __attribute__((ext_vector_type(4))) unsigned short ushort4v;

__device__ __forceinline__ float lrelu(float v) { return v >= 0.f ? v : 0.01f * v; }

__device__ __forceinline__ unsigned short f2bf(float x) {
    union { float f; unsigned u; } c; c.f = x;
    unsigned r = (c.u + 0x7FFFu + ((c.u >> 16) & 1u)) >> 16;
    return (unsigned short)r;
}
__device__ __forceinline__ float bf2f(unsigned short h) {
    union { unsigned u; float f; } c; c.u = ((unsigned)h) << 16;
    return c.f;
}

// async global->LDS, 16B per lane. LDS dest must be wave-uniform base
// (HW adds lane*16); global src is per-lane (pre-swizzled).
__device__ __forceinline__ void gload16(const unsigned short* g, unsigned short* l) {
    __builtin_amdgcn_global_load_lds(
        (const __attribute__((address_space(1))) unsigned int*)g,
        (__attribute__((address_space(3))) unsigned int*)l, 16, 0, 0);
}

// ===========================================================================
// Shared MFMA core (r15: K-range arg for split-K): C[128x128] += A.B^T over
// K in [kBeg,kEnd), split-bf16 (hh+hl+lh ~ fp32). 256 threads, 4 waves 2x2.
// LDS: 4 tiles [128][64]. gload_lds direct staging, both-sides XOR swizzle.
// ===========================================================================
__device__ __forceinline__ void mfma_core(
    const unsigned short* __restrict__ Ah, const unsigned short* __restrict__ Al, int lda,
    const unsigned short* __restrict__ Bh, const unsigned short* __restrict__ Bl, int ldb,
    unsigned short* lds, float4v acc[4][4], int kBeg, int kEnd) {
    const int tid = threadIdx.x;
    const int lane = tid & 63, wave = tid >> 6;
    const int wm = wave >> 1, wn = wave & 1;
    const int l15 = lane & 15, lhi = lane >> 4;
    unsigned short* LAh = lds;
    unsigned short* LAl = lds + 8192;
    unsigned short* LBh = lds + 16384;
    unsigned short* LBl = lds + 24576;

    for (int k0 = kBeg; k0 < kEnd; k0 += 64) {
#pragma unroll
        for (int tile = 0; tile < 4; ++tile) {
            const unsigned short* s = (tile == 0) ? Ah : (tile == 1) ? Al : (tile == 2) ? Bh : Bl;
            int ld = (tile < 2) ? lda : ldb;
            unsigned short* dbase = lds + tile * 8192;
#pragma unroll
            for (int it = 0; it < 4; ++it) {
                int idx = it * 256 + tid;
                int row = idx >> 3, ch = idx & 7;
                gload16(&s[row * ld + k0 + ((ch ^ (row & 7)) << 3)],
                        dbase + ((it * 256 + wave * 64) << 3));
            }
        }
        __syncthreads();
#pragma unroll
        for (int ks = 0; ks < 2; ++ks) {
            short8 ah[4], al[4], bh[4], bl[4];
#pragma unroll
            for (int m = 0; m < 4; ++m) {
                int r = wm * 64 + m * 16 + l15;
                int off = r * 64 + (((ks * 4 + lhi) ^ (r & 7)) * 8);
                ah[m] = *(const short8*)&LAh[off];
                al[m] = *(const short8*)&LAl[off];
            }
#pragma unroll
            for (int n = 0; n < 4; ++n) {
                int r = wn * 64 + n * 16 + l15;
                int off = r * 64 + (((ks * 4 + lhi) ^ (r & 7)) * 8);
                bh[n] = *(const short8*)&LBh[off];
                bl[n] = *(const short8*)&LBl[off];
            }
#pragma unroll
            for (int m = 0; m < 4; ++m)
#pragma unroll
                for (int n = 0; n < 4; ++n) {
                    acc[m][n] = __builtin_amdgcn_mfma_f32_16x16x32_bf16(ah[m], bh[n], acc[m][n], 0, 0, 0);
                    acc[m][n] = __builtin_amdgcn_mfma_f32_16x16x32_bf16(ah[m], bl[n], acc[m][n], 0, 0, 0);
                    acc[m][n] = __builtin_amdgcn_mfma_f32_16x16x32_bf16(al[m], bh[n], acc[m][n], 0, 0, 0);
                }
        }
        __syncthreads();
    }
}

// ---------------------------------------------------------------------------
// Fused weight splits: grid (16,16,6), block (32,8).
// z 0-2: transpose-split theta/phi/g_w; z 3-5: straight-split W_w/p1/p2.
// ---------------------------------------------------------------------------
__global__ __launch_bounds__(256) void k_splitw6(
    const float* __restrict__ tw, const float* __restrict__ fw,
    const float* __restrict__ gw, const float* __restrict__ ww,
    const float* __restrict__ p1w, const float* __restrict__ p2w,
    unsigned short* __restrict__ TtH, unsigned short* __restrict__ TtL,
    unsigned short* __restrict__ PtH, unsigned short* __restrict__ PtL,
    unsigned short* __restrict__ GtH, unsigned short* __restrict__ GtL,
    unsigned short* __restrict__ WwH, unsigned short* __restrict__ WwL,
    unsigned short* __restrict__ p1h, unsigned short* __restrict__ p1l,
    unsigned short* __restrict__ p2h, unsigned short* __restrict__ p2l) {
    int z = blockIdx.z;
    int i0 = blockIdx.x * 32, k0 = blockIdx.y * 32;
    int tx = threadIdx.x, ty = threadIdx.y;
    __shared__ float tile[32][33];
    if (z < 3) {
        const float* src = (z == 0) ? tw : (z == 1) ? fw : gw;
        unsigned short* dh = (z == 0) ? TtH : (z == 1) ? PtH : GtH;
        unsigned short* dl = (z == 0) ? TtL : (z == 1) ? PtL : GtL;
#pragma unroll
        for (int i = 0; i < 4; ++i)
            tile[ty + i * 8][tx] = src[(k0 + ty + i * 8) * 512 + i0 + tx];
        __syncthreads();
#pragma unroll
        for (int i = 0; i < 4; ++i) {
            int row = i0 + ty + i * 8;
            float v = tile[tx][ty + i * 8];
            unsigned short h = f2bf(v), l = f2bf(v - bf2f(h));
            int idx = row * 512 + k0 + tx;
            dh[idx] = h;
            dl[idx] = l;
        }
    } else {
        const float* src = (z == 3) ? ww : (z == 4) ? p1w : p2w;
        unsigned short* dh = (z == 3) ? WwH : (z == 4) ? p1h : p2h;
        unsigned short* dl = (z == 3) ? WwL : (z == 4) ? p1l : p2l;
#pragma unroll
        for (int i = 0; i < 4; ++i) {
            int r = k0 + ty + i * 8;
            int idx = r * 512 + i0 + tx;
            float v = src[idx];
            unsigned short h = f2bf(v), l = f2bf(v - bf2f(h));
            dh[idx] = h;
            dl[idx] = l;
        }
    }
}

// ---------------------------------------------------------------------------
// Weight GEMMs, split-K=4 (r15): grid (4,4,8): z = wg*4 + kslice.
//   wg=1: Mw = Tt.Pt^T -> partial rows 0-511; wg=0: Wg_w = Ww.Gt^T -> 512-1023
// fp32 partials Pw[kslice][1024*512].
// ---------------------------------------------------------------------------
__global__ __launch_bounds__(256) void k_wgemm_sk(
    const unsigned short* __restrict__ WwH, const unsigned short* __restrict__ WwL,
    const unsigned short* __restrict__ GtH, const unsigned short* __restrict__ GtL,
    const unsigned short* __restrict__ TtH, const unsigned short* __restrict__ TtL,
    const unsigned short* __restrict__ PtH, const unsigned short* __restrict__ PtL,
    float* __restrict__ Pw) {
    __shared__ unsigned short lds[32768];
    int i0 = blockIdx.y * 128, j0 = blockIdx.x * 128;
    int wg = blockIdx.z >> 2, kslice = blockIdx.z & 3;
    const unsigned short* Ah = (wg == 0 ? WwH : TtH) + i0 * 512;
    const unsigned short* Al = (wg == 0 ? WwL : TtL) + i0 * 512;
    const unsigned short* Bh = (wg == 0 ? GtH : PtH) + j0 * 512;
    const unsigned short* Bl = (wg == 0 ? GtL : PtL) + j0 * 512;
    float4v acc[4][4];
#pragma unroll
    for (int m = 0; m < 4; ++m)
#pragma unroll
        for (int n = 0; n < 4; ++n) acc[m][n] = (float4v){0.f, 0.f, 0.f, 0.f};

    mfma_core(Ah, Al, 512, Bh, Bl, 512, lds, acc, kslice * 128, kslice * 128 + 128);

    int lane = threadIdx.x & 63, wave = threadIdx.x >> 6;
    int wm = wave >> 1, wn = wave & 1, l15 = lane & 15, lhi = lane >> 4;
    int rowbase = (wg == 0) ? 512 + i0 : i0;
    float* P = Pw + kslice * 524288;
#pragma unroll
    for (int m = 0; m < 4; ++m)
#pragma unroll
        for (int n = 0; n < 4; ++n) {
            int bcol = j0 + wn * 64 + n * 16 + l15;
#pragma unroll
            for (int i = 0; i < 4; ++i) {
                int r = rowbase + wm * 64 + m * 16 + lhi * 4 + i;
                P[r * 512 + bcol] = acc[m][n][i];
            }
        }
}

// ---------------------------------------------------------------------------
// Partial reduce: sum NPART fp32 partials (stride floats apart).
// MODE 0: split->Ch/Cl. MODE 1: lrelu+split. MODE 2: lrelu+fp32->Cf.
// grid n/1024, block 256, float4 per thread.
// ---------------------------------------------------------------------------
template <int NPART, int MODE>
__global__ __launch_bounds__(256) void k_red(
    const float* __restrict__ P, int stride,
    unsigned short* __restrict__ Ch, unsigned short* __restrict__ Cl,
    float* __restrict__ Cf) {
    int i4 = blockIdx.x * 256 + threadIdx.x;
    float4v v = ((const float4v*)P)[i4];
#pragma unroll
    for (int p = 1; p < NPART; ++p) {
        float4v u = ((const float4v*)(P + (size_t)p * stride))[i4];
#pragma unroll
        for (int j = 0; j < 4; ++j) v[j] += u[j];
    }
    if (MODE >= 1) {
#pragma unroll
        for (int j = 0; j < 4; ++j) v[j] = lrelu(v[j]);
    }
    if (MODE == 2) {
        ((float4v*)Cf)[i4] = v;
    } else {
        ushort4v h, l;
#pragma unroll
        for (int j = 0; j < 4; ++j) {
            h[j] = f2bf(v[j]);
            l[j] = f2bf(v[j] - bf2f(h[j]));
        }
        ((ushort4v*)Ch)[i4] = h;
        ((ushort4v*)Cl)[i4] = l;
    }
}

// ---------------------------------------------------------------------------
// Transpose+split inputs: Xt[((b*128+t)*3+k)*512 + c] = in_k[b][c][t]
// (bf16 hi/lo + fp32 copy Xf for k_mix's residual path).
// ---------------------------------------------------------------------------
__global__ __launch_bounds__(256) void k_splitx(const float* __restrict__ o1,
                                                const float* __restrict__ o2,
                                                const float* __restrict__ o3,
                                                unsigned short* __restrict__ Xh,
                                                unsigned short* __restrict__ Xl,
                                                float* __restrict__ Xf) {
    int z = blockIdx.z;
    int b = z / 3, k = z - b * 3;
    const float* In = (k == 0) ? o1 : ((k == 1) ? o2 : o3);
    int c0 = blockIdx.x * 32, t0 = blockIdx.y * 32;
    __shared__ float tile[32][33];
    int tx = threadIdx.x, ty = threadIdx.y;
#pragma unroll
    for (int i = 0; i < 4; ++i)
        tile[ty + i * 8][tx] = In[(b * 512 + c0 + ty + i * 8) * 128 + t0 + tx];
    __syncthreads();
#pragma unroll
    for (int i = 0; i < 4; ++i) {
        int t = t0 + ty + i * 8;
        float v = tile[tx][ty + i * 8];
        unsigned short h = f2bf(v), l = f2bf(v - bf2f(h));
        int idx = ((b * 128 + t) * 3 + k) * 512 + c0 + tx;
        Xh[idx] = h;
        Xl[idx] = l;
        Xf[idx] = v;
    }
}

// ---------------------------------------------------------------------------
// Stage A via MFMA: grid (48, 8): x = b*3+kin, y = o-tile
//   y 0-3 -> Y = Mw . x (bf16 hi/lo), y 4-7 -> Wg = Wg_w . x (fp32)
// ---------------------------------------------------------------------------
__global__ __launch_bounds__(256) void k_ga(
    const unsigned short* __restrict__ Whi, const unsigned short* __restrict__ Wlo,
    const unsigned short* __restrict__ Xh, const unsigned short* __restrict__ Xl,
    unsigned short* __restrict__ Yh, unsigned short* __restrict__ Yl,
    float* __restrict__ Wg) {
    __shared__ unsigned short lds[32768];
    int bk = blockIdx.x, y = blockIdx.y;
    int b = bk / 3, kin = bk - b * 3;
    int bbase = (b * 384 + kin) * 512;
    float4v acc[4][4];
#pragma unroll
    for (int m = 0; m < 4; ++m)
#pragma unroll
        for (int n = 0; n < 4; ++n) acc[m][n] = (float4v){0.f, 0.f, 0.f, 0.f};

    mfma_core(Whi + y * 128 * 512, Wlo + y * 128 * 512, 512,
              Xh + bbase, Xl + bbase, 1536, lds, acc, 0, 512);

    int lane = threadIdx.x & 63, wave = threadIdx.x >> 6;
    int wm = wave >> 1, wn = wave & 1, l15 = lane & 15, lhi = lane >> 4;
    int wsel = y >> 2, o0 = (y & 3) * 128;
#pragma unroll
    for (int m = 0; m < 4; ++m)
#pragma unroll
        for (int n = 0; n < 4; ++n) {
            int o_in = wm * 64 + m * 16 + lhi * 4;
            int t = wn * 64 + n * 16 + l15;
            int idx = bbase + t * 1536 + o0 + o_in;
            if (wsel == 1) {
                *(float4v*)&Wg[idx] = acc[m][n];
            } else {
                ushort4v h, l;
#pragma unroll
                for (int i = 0; i < 4; ++i) {
                    float v = acc[m][n][i];
                    h[i] = f2bf(v);
                    l[i] = f2bf(v - bf2f(h[i]));
                }
                *(ushort4v*)&Yh[idx] = h;
                *(ushort4v*)&Yl[idx] = l;
            }
        }
}

// ---------------------------------------------------------------------------
// Band gram: k_mix only reads |t1-t2|<=7, so compute only the band.
// grid 1152 = (mat, t1-chunk c) XCD-swizzled, block 64 (1 wave).
// ---------------------------------------------------------------------------
__global__ __launch_bounds__(64) void k_gram3(
    const unsigned short* __restrict__ Xh, const unsigned short* __restrict__ Xl,
    const unsigned short* __restrict__ Yh, const unsigned short* __restrict__ Yl,
    float* __restrict__ D) {
    __shared__ unsigned short lds[8192];
    int orig = blockIdx.x;
    int idx = (orig & 7) * 144 + (orig >> 3);  // 1152 = 8*144, bijective
    int mat = idx >> 3, c = idx & 7;
    int b = mat / 9, r9 = mat - b * 9, k = r9 / 3, kp = r9 - k * 3;
    const unsigned short* Ahg = Xh + (b * 384 + k) * 512;
    const unsigned short* Alg = Xl + (b * 384 + k) * 512;
    const unsigned short* Bhg = Yh + (b * 384 + kp) * 512;
    const unsigned short* Blg = Yl + (b * 384 + kp) * 512;
    int t1b = c * 16, t2b0 = c * 16 - 16;
    unsigned short* LAh = lds;          // [16][64]
    unsigned short* LAl = lds + 1024;
    unsigned short* LBh = lds + 2048;   // [48][64]
    unsigned short* LBl = lds + 5120;
    int tid = threadIdx.x;
    int l15 = tid & 15, lhi = tid >> 4;
    float4v acc[3];
    acc[0] = (float4v){0.f, 0.f, 0.f, 0.f};
    acc[1] = (float4v){0.f, 0.f, 0.f, 0.f};
    acc[2] = (float4v){0.f, 0.f, 0.f, 0.f};

    for (int k0 = 0; k0 < 512; k0 += 64) {
#pragma unroll
        for (int it = 0; it < 2; ++it) {
            int i2 = it * 64 + tid;
            int row = i2 >> 3, ch = i2 & 7;
            int g = (t1b + row) * 1536 + k0 + ((ch ^ (row & 7)) << 3);
            gload16(&Ahg[g], LAh + ((it * 64) << 3));
            gload16(&Alg[g], LAl + ((it * 64) << 3));
        }
#pragma unroll
        for (int it = 0; it < 6; ++it) {
            int i2 = it * 64 + tid;
            int row = i2 >> 3, ch = i2 & 7;
            int t2 = t2b0 + row;
            int t2c = t2 < 0 ? 0 : (t2 > 127 ? 127 : t2);
            int g = t2c * 1536 + k0 + ((ch ^ (row & 7)) << 3);
            gload16(&Bhg[g], LBh + ((it * 64) << 3));
            gload16(&Blg[g], LBl + ((it * 64) << 3));
        }
        __syncthreads();
#pragma unroll
        for (int ks = 0; ks < 2; ++ks) {
            int offa = l15 * 64 + (((ks * 4 + lhi) ^ (l15 & 7)) * 8);
            short8 ah = *(const short8*)&LAh[offa];
            short8 al = *(const short8*)&LAl[offa];
#pragma unroll
            for (int tl = 0; tl < 3; ++tl) {
                int rb = tl * 16 + l15;
                int offb = rb * 64 + (((ks * 4 + lhi) ^ (rb & 7)) * 8);
                short8 bh = *(const short8*)&LBh[offb];
                short8 bl = *(const short8*)&LBl[offb];
                acc[tl] = __builtin_amdgcn_mfma_f32_16x16x32_bf16(ah, bh, acc[tl], 0, 0, 0);
                acc[tl] = __builtin_amdgcn_mfma_f32_16x16x32_bf16(ah, bl, acc[tl], 0, 0, 0);
                acc[tl] = __builtin_amdgcn_mfma_f32_16x16x32_bf16(al, bh, acc[tl], 0, 0, 0);
            }
        }
        __syncthreads();
    }
    float* Dm = D + mat * 16384;
#pragma unroll
    for (int tl = 0; tl < 3; ++tl) {
        int t2base = t2b0 + tl * 16;
        if (t2base < 0 || t2base > 127) continue;
        int t2 = t2base + l15;
#pragma unroll
        for (int i = 0; i < 4; ++i) {
            int t1 = t1b + lhi * 4 + i;
            Dm[t1 * 128 + t2] = acc[tl][i];
        }
    }
}

// ---------------------------------------------------------------------------
// MLP layer, split-K=2 (r15): grid (16,4,2): z = kslice (K 256 each).
// fp32 partials Pp[kslice][2048*512]; activation applied in k_red after sum.
// ---------------------------------------------------------------------------
__global__ __launch_bounds__(256) void k_mlp_sk(
    const unsigned short* __restrict__ Ahi, const unsigned short* __restrict__ Alo,
    const unsigned short* __restrict__ Bhi, const unsigned short* __restrict__ Blo,
    float* __restrict__ Pp) {
    __shared__ unsigned short lds[32768];
    int r0 = blockIdx.x * 128, o0 = blockIdx.y * 128;
    int kslice = blockIdx.z;
    float4v acc[4][4];
#pragma unroll
    for (int m = 0; m < 4; ++m)
#pragma unroll
        for (int n = 0; n < 4; ++n) acc[m][n] = (float4v){0.f, 0.f, 0.f, 0.f};

    mfma_core(Ahi + r0 * 512, Alo + r0 * 512, 512, Bhi + o0 * 512, Blo + o0 * 512, 512,
              lds, acc, kslice * 256, kslice * 256 + 256);

    int lane = threadIdx.x & 63, wave = threadIdx.x >> 6;
    int wm = wave >> 1, wn = wave & 1, l15 = lane & 15, lhi = lane >> 4;
    float* P = Pp + (size_t)kslice * 1048576;
#pragma unroll
    for (int m = 0; m < 4; ++m)
#pragma unroll
        for (int n = 0; n < 4; ++n) {
            int o = o0 + wn * 64 + n * 16 + l15;
#pragma unroll
            for (int i = 0; i < 4; ++i) {
                int r = r0 + wm * 64 + m * 16 + lhi * 4 + i;
                P[r * 512 + o] = acc[m][n][i];
            }
        }
}

// ---------------------------------------------------------------------------
// Mix, 4 t's per block: gather band f, softmax (96-way), union preload,
// float4 Pm reads. grid 512 XCD-swizzled, block 512, one o per thread.
// ---------------------------------------------------------------------------
__global__ __launch_bounds__(512) void k_mix(
    const float* __restrict__ Xf, const float* __restrict__ Wg,
    const float* __restrict__ D, const float* __restrict__ W_b,
    unsigned short* __restrict__ Plh, unsigned short* __restrict__ Pll) {
    int orig = blockIdx.x;
    int bid = ((orig & 7) << 6) | (orig >> 3);  // 512 = 8 * 64, bijective
    int b = bid >> 5, tg = bid & 31;
    int t0 = tg * 4;
    int tid = threadIdx.x;

    __shared__ float Pm[4][24][28];

    for (int idx = tid; idx < 4 * 576; idx += 512) {
        int dt = idx / 576, r = idx - dt * 576;
        int n = r / 24, m = r - n * 24;
        int t = t0 + dt;
        int j = n / 3, k = n - j * 3;
        int jp = m / 3, kp = m - jp * 3;
        int t1 = t - 7 + j, t2 = t - 7 + jp;
        float v = 0.f;
        if (t1 >= 0 && t2 >= 0)
            v = D[((((b * 3 + k) * 3 + kp) * 128 + t1) << 7) + t2];
        Pm[dt][n][m] = v;
    }
    __syncthreads();

    if (tid < 96) {
        int dt = tid / 24, n = tid - dt * 24;
        float mx = -1e30f;
#pragma unroll
        for (int m = 0; m < 24; ++m) mx = fmaxf(mx, Pm[dt][n][m]);
        float e[24], sum = 0.f;
#pragma unroll
        for (int m = 0; m < 24; ++m) { e[m] = __expf(Pm[dt][n][m] - mx); sum += e[m]; }
        float inv = 1.0f / sum;
#pragma unroll
        for (int m = 0; m < 24; ++m) Pm[dt][n][m] = e[m] * inv;
    }
    __syncthreads();

    int o = tid;
    float wg[33], xw[33];
#pragma unroll
    for (int s = 0; s < 11; ++s) {
        int tp = t0 - 7 + s;
#pragma unroll
        for (int k = 0; k < 3; ++k) {
            int base = (((b * 128 + tp) * 3 + k) << 9) + o;
            bool ok = (tp >= 0);
            wg[s * 3 + k] = ok ? Wg[base] : 0.f;
            xw[s * 3 + k] = ok ? Xf[base] : 0.f;
        }
    }
    float wb = W_b[o];
#pragma unroll
    for (int dt = 0; dt < 4; ++dt) {
        float pooled = -1e30f;
#pragma unroll
        for (int n = 0; n < 24; ++n) {
            float s0 = 0.f, s1 = 0.f, s2 = 0.f, s3 = 0.f;
#pragma unroll
            for (int mq = 0; mq < 6; ++mq) {
                float4 p4 = *(const float4*)&Pm[dt][n][mq * 4];
                s0 += p4.x * wg[mq * 4 + 0 + dt * 3];
                s1 += p4.y * wg[mq * 4 + 1 + dt * 3];
                s2 += p4.z * wg[mq * 4 + 2 + dt * 3];
                s3 += p4.w * wg[mq * 4 + 3 + dt * 3];
            }
            float s = ((s0 + s1) + (s2 + s3)) + wb + xw[n + dt * 3];
            pooled = fmaxf(pooled, s);
        }
        int t = t0 + dt;
        int oidx = ((t * 16 + b) << 9) + o;
        unsigned short h = f2bf(pooled), l = f2bf(pooled - bf2f(h));
        Plh[oidx] = h;
        Pll[oidx] = l;
    }
}

// ---------------------------------------------------------------------------
// out[r] = lrelu( sum_c H[r][c]*p3w[c] + p3b )   one wave per row
// ---------------------------------------------------------------------------
__global__ __launch_bounds__(256) void k_final(const float* __restrict__ H,
                                               const float* __restrict__ p3w,
                                               const float* __restrict__ p3b,
                                               float* __restrict__ out) {
    int r = blockIdx.x * 4 + (threadIdx.x >> 6);
    int lane = threadIdx.x & 63;
    const float4* h4 = (const float4*)&H[r << 9];
    const float4* w4 = (const float4*)p3w;
    float4 a1 = h4[lane], a2 = h4[lane + 64];
    float4 b1 = w4[lane], b2 = w4[lane + 64];
    float s = a1.x * b1.x + a1.y * b1.y + a1.z * b1.z + a1.w * b1.w +
              a2.x * b2.x + a2.y * b2.y + a2.z * b2.z + a2.w * b2.w;
#pragma unroll
    for (int off = 32; off; off >>= 1) s += __shfl_down(s, off, 64);
    if (lane == 0) out[r] = lrelu(s + p3b[0]);
}

extern "C" void kernel_launch(void* const* d_in, const int* in_sizes, int n_in,
                              void* d_out, int out_size, void* d_ws, size_t ws_size,
                              hipStream_t stream) {
    const float* out1 = (const float*)d_in[0];
    const float* out2 = (const float*)d_in[1];
    const float* out3 = (const float*)d_in[2];
    const float* theta_w = (const float*)d_in[3];
    const float* phi_w = (const float*)d_in[4];
    const float* g_w = (const float*)d_in[5];
    const float* W_w = (const float*)d_in[6];
    const float* W_b = (const float*)d_in[7];
    const float* p1_w = (const float*)d_in[8];
    const float* p2_w = (const float*)d_in[9];
    const float* p3_w = (const float*)d_in[10];
    const float* p3_b = (const float*)d_in[11];
    float* outp = (float*)d_out;

    // ---- workspace layout (bytes) ----
    char* wsb = (char*)d_ws;
    unsigned short* Whi = (unsigned short*)(wsb + 0);         // 1024x512 bf16 (Mw | Wg_w)
    unsigned short* Wlo = (unsigned short*)(wsb + 1048576);
    unsigned short* p1h = (unsigned short*)(wsb + 2097152);
    unsigned short* p1l = (unsigned short*)(wsb + 2621440);
    unsigned short* p2h = (unsigned short*)(wsb + 3145728);
    unsigned short* p2l = (unsigned short*)(wsb + 3670016);
    unsigned short* WwH = (unsigned short*)(wsb + 4194304);
    unsigned short* WwL = (unsigned short*)(wsb + 4718592);
    unsigned short* TtH = (unsigned short*)(wsb + 5242880);
    unsigned short* TtL = (unsigned short*)(wsb + 5767168);
    unsigned short* PtH = (unsigned short*)(wsb + 6291456);
    unsigned short* PtL = (unsigned short*)(wsb + 6815744);
    unsigned short* GtH = (unsigned short*)(wsb + 7340032);
    unsigned short* GtL = (unsigned short*)(wsb + 7864320);
    unsigned short* Xh  = (unsigned short*)(wsb + 8388608);   // 6144x512 bf16
    unsigned short* Xl  = (unsigned short*)(wsb + 14680064);
    unsigned short* Yh  = (unsigned short*)(wsb + 20971520);  // 6144x512 bf16
    unsigned short* Yl  = (unsigned short*)(wsb + 27262976);
    float* Wg = (float*)(wsb + 33554432);                     // 6144x512 fp32 (also wgemm partials pre-k_ga)
    float* D  = (float*)(wsb + 46137344);                     // 144x128x128 fp32 (also MLP partials post-k_mix)
    float* Xf = (float*)(wsb + 55574528);                     // 6144x512 fp32
    // aliases (dead-buffer reuse):
    float* Pw = Wg;                                           // 4x 1024x512 fp32 partials (8 MB), dead before k_ga writes Wg
    float* Pp = D;                                            // 2x 2048x512 fp32 partials (8 MB), D dead after k_mix
    unsigned short* Plh = (unsigned short*)(wsb + 20971520);  // over Yh (dead after gram)
    unsigned short* Pll = (unsigned short*)(wsb + 23068672);
    unsigned short* h1h = (unsigned short*)(wsb + 27262976);  // over Yl (dead after gram)
    unsigned short* h1l = (unsigned short*)(wsb + 29360128);
    float* h2 = (float*)(wsb + 8388608);                      // over Xh (dead after mix)

    // 1. fused weight splits
    k_splitw6<<<dim3(16, 16, 6), dim3(32, 8), 0, stream>>>(
        theta_w, phi_w, g_w, W_w, p1_w, p2_w,
        TtH, TtL, PtH, PtL, GtH, GtL, WwH, WwL, p1h, p1l, p2h, p2l);
    // 2. transpose+split inputs (+ fp32 Xf copy)
    k_splitx<<<dim3(16, 4, 48), dim3(32, 8), 0, stream>>>(out1, out2, out3, Xh, Xl, Xf);
    // 3. weight GEMMs split-K=4 -> fp32 partials -> reduce+split into Whi/Wlo
    k_wgemm_sk<<<dim3(4, 4, 8), 256, 0, stream>>>(WwH, WwL, GtH, GtL, TtH, TtL,
                                                  PtH, PtL, Pw);
    k_red<4, 0><<<dim3(512), 256, 0, stream>>>(Pw, 524288, Whi, Wlo, nullptr);
    // 4. stage A: Y (bf16 hi/lo) + Wg (fp32) — overwrites Pw region (dead)
    k_ga<<<dim3(48, 8), 256, 0, stream>>>(Whi, Wlo, Xh, Xl, Yh, Yl, Wg);
    // 5. band gram matrices: D = X . Y^T, |t1-t2| <= 7 only
    k_gram3<<<dim3(1152), 64, 0, stream>>>(Xh, Xl, Yh, Yl, D);
    // 6. softmax + mix + residual + pool (4 t's per block)
    k_mix<<<dim3(512), 512, 0, stream>>>(Xf, Wg, D, W_b, Plh, Pll);
    // 7. MLP1 split-K=2 -> partials in D region (dead) -> reduce+lrelu+split
    k_mlp_sk<<<dim3(16, 4, 2), 256, 0, stream>>>(Plh, Pll, p1h, p1l, Pp);
    k_red<2, 1><<<dim3(1024), 256, 0, stream>>>(Pp, 1048576, h1h, h1l, nullptr);
    // 8. MLP2 split-K=2 -> reduce+lrelu -> h2 fp32
    k_mlp_sk<<<dim3(16, 4, 2), 256, 0, stream>>>(h1h, h1l, p2h, p2l, Pp);
    k_red<2, 2><<<dim3(1024), 256, 0, stream>>>(Pp, 1048576, nullptr, nullptr, h2);
    // 9. final projection
    k_final<<<dim3(512), 256, 0, stream>>>(h2, p3_w, p3_b, outp);
}